// Round 2
// baseline (2283.809 us; speedup 1.0000x reference)
//
#include <hip/hip_runtime.h>
#include <math.h>

#define K_NBR 20
#define BN_EPS 1e-5f
#define NPTS 1024
#define NB 8

__device__ __forceinline__ float lrelu_f(float v) { return v >= 0.f ? v : 0.2f * v; }

// ---------------- transpose x [B,3,N] -> xt [B,N,3] ----------------
__global__ void transpose_kernel(const float* __restrict__ x, float* __restrict__ xt) {
  int i = blockIdx.x * 256 + threadIdx.x;
  if (i >= NB * 3 * NPTS) return;
  int b = i / (3 * NPTS);
  int rem = i - b * 3 * NPTS;
  int c = rem / NPTS;
  int n = rem - c * NPTS;
  xt[((size_t)b * NPTS + n) * 3 + c] = x[i];
}

// ---------------- row squared norms ----------------
__global__ void rowsq_kernel(const float* __restrict__ X, int stride, int C,
                             float* __restrict__ xx) {
  int i = blockIdx.x * 256 + threadIdx.x;
  if (i >= NB * NPTS) return;
  const float* r = X + (size_t)i * stride;
  float s = 0.f;
  for (int c = 0; c < C; ++c) s += r[c] * r[c];
  xx[i] = s;
}

// ---------------- tiled f32 NT-GEMM: C[r,o] = sum_k A[r,k]*B[o,k] ----------------
// 64x64 tile, BK=32, 256 threads, 4x4 per thread. Optional per-column stats.
__device__ __forceinline__ float4 load_guard4(const float* __restrict__ rowp, int c, int K) {
  float4 v;
  if (c + 4 <= K) {
    v = *(const float4*)&rowp[c];
  } else {
    v.x = (c + 0 < K) ? rowp[c + 0] : 0.f;
    v.y = (c + 1 < K) ? rowp[c + 1] : 0.f;
    v.z = (c + 2 < K) ? rowp[c + 2] : 0.f;
    v.w = (c + 3 < K) ? rowp[c + 3] : 0.f;
  }
  return v;
}

__global__ __launch_bounds__(256) void gemm_nt_kernel(
    const float* __restrict__ A, const float* __restrict__ B, float* __restrict__ Cm,
    int M, int N, int K, int lda, int ldb, int ldc,
    long batchA, long batchB, long batchC,
    float* __restrict__ ssum, float* __restrict__ ssq) {
  const float* Ab = A + (size_t)blockIdx.z * batchA;
  const float* Bb = B + (size_t)blockIdx.z * batchB;
  float* Cb = Cm + (size_t)blockIdx.z * batchC;
  __shared__ float As[64][36];
  __shared__ float Bs[64][36];
  int t = threadIdx.x;
  int tx = t & 15, ty = t >> 4;
  int bm = blockIdx.y * 64, bn = blockIdx.x * 64;
  float acc[4][4] = {};
  for (int k0 = 0; k0 < K; k0 += 32) {
#pragma unroll
    for (int i = 0; i < 2; ++i) {
      int li = t * 2 + i;             // 0..511 float4 slots
      int r = li >> 3;
      int c = (li & 7) << 2;
      float4 va = load_guard4(Ab + (size_t)(bm + r) * lda, k0 + c, K);
      As[r][c] = va.x; As[r][c + 1] = va.y; As[r][c + 2] = va.z; As[r][c + 3] = va.w;
      float4 vb = load_guard4(Bb + (size_t)(bn + r) * ldb, k0 + c, K);
      Bs[r][c] = vb.x; Bs[r][c + 1] = vb.y; Bs[r][c + 2] = vb.z; Bs[r][c + 3] = vb.w;
    }
    __syncthreads();
#pragma unroll
    for (int kc = 0; kc < 32; kc += 4) {
      float4 a4[4], b4[4];
#pragma unroll
      for (int i = 0; i < 4; ++i) a4[i] = *(const float4*)&As[ty + 16 * i][kc];
#pragma unroll
      for (int j = 0; j < 4; ++j) b4[j] = *(const float4*)&Bs[tx + 16 * j][kc];
#pragma unroll
      for (int i = 0; i < 4; ++i)
#pragma unroll
        for (int j = 0; j < 4; ++j)
          acc[i][j] += a4[i].x * b4[j].x + a4[i].y * b4[j].y +
                       a4[i].z * b4[j].z + a4[i].w * b4[j].w;
    }
    __syncthreads();
  }
#pragma unroll
  for (int i = 0; i < 4; ++i) {
    int r = bm + ty + 16 * i;
#pragma unroll
    for (int j = 0; j < 4; ++j) {
      int o = bn + tx + 16 * j;
      Cb[(size_t)r * ldc + o] = acc[i][j];
    }
  }
  if (ssum != nullptr) {
#pragma unroll
    for (int j = 0; j < 4; ++j) {
      int o = bn + tx + 16 * j;
      float s = 0.f, s2 = 0.f;
#pragma unroll
      for (int i = 0; i < 4; ++i) { s += acc[i][j]; s2 += acc[i][j] * acc[i][j]; }
      atomicAdd(&ssum[o], s);
      atomicAdd(&ssq[o], s2);
    }
  }
}

// ---------------- top-k (k=20) selection with jax tie rule (lower index wins) ------
__global__ __launch_bounds__(256) void topk_kernel(
    const float* __restrict__ inner, const float* __restrict__ xx, int* __restrict__ idxb) {
  int b = blockIdx.y, n = blockIdx.x, t = threadIdx.x;
  __shared__ float nd[NPTS];
  __shared__ float rv[256];
  __shared__ int ri[256];
  float xxn = xx[b * NPTS + n];
  const float* row = inner + ((size_t)b * NPTS + n) * NPTS;
  for (int m = t; m < NPTS; m += 256)
    nd[m] = 2.f * row[m] - xxn - xx[b * NPTS + m];
  __syncthreads();
  for (int kk = 0; kk < K_NBR; ++kk) {
    float bv = -__builtin_inff(); int bi = NPTS;
    for (int m = t; m < NPTS; m += 256) {
      float v = nd[m];
      if (v > bv || (v == bv && m < bi)) { bv = v; bi = m; }
    }
    rv[t] = bv; ri[t] = bi;
    __syncthreads();
    for (int s = 128; s > 0; s >>= 1) {
      if (t < s) {
        float ov = rv[t + s]; int oi = ri[t + s];
        if (ov > rv[t] || (ov == rv[t] && oi < ri[t])) { rv[t] = ov; ri[t] = oi; }
      }
      __syncthreads();
    }
    if (t == 0) {
      idxb[((size_t)b * NPTS + n) * K_NBR + kk] = ri[0];
      nd[ri[0]] = -__builtin_inff();
    }
    __syncthreads();
  }
}

// ---------------- edge conv: h = W * [nbr-center; center], emit max/min + stats ----
template <int C, int O, int TPB>
__global__ __launch_bounds__(TPB) void edgeconv_kernel(
    const float* __restrict__ X, int stride, const int* __restrict__ idxb,
    const float* __restrict__ W, float* __restrict__ hmax, float* __restrict__ hmin,
    float* __restrict__ ssum, float* __restrict__ ssq) {
  constexpr int OPT = O / TPB;
  int b = blockIdx.y, n = blockIdx.x, t = threadIdx.x;
  __shared__ float center[C];
  __shared__ float diff[K_NBR][C];
  __shared__ int sidx[K_NBR];
  const float* xrow = X + ((size_t)b * NPTS + n) * stride;
  for (int c = t; c < C; c += TPB) center[c] = xrow[c];
  if (t < K_NBR) sidx[t] = idxb[((size_t)b * NPTS + n) * K_NBR + t];
  __syncthreads();
  for (int i = t; i < K_NBR * C; i += TPB) {
    int kk = i / C, c = i - kk * C;
    diff[kk][c] = X[((size_t)b * NPTS + sidx[kk]) * stride + c] - center[c];
  }
  __syncthreads();

  float h[OPT][K_NBR];
#pragma unroll
  for (int j = 0; j < OPT; ++j) {
    int o = t + j * TPB;
    float wc = 0.f;
    for (int c = 0; c < C; ++c) wc += W[(size_t)o * 2 * C + C + c] * center[c];
#pragma unroll
    for (int kk = 0; kk < K_NBR; ++kk) h[j][kk] = wc;
  }

  if constexpr (C % 4 == 0) {
    for (int c = 0; c < C; c += 4) {
      float4 w4[OPT];
#pragma unroll
      for (int j = 0; j < OPT; ++j)
        w4[j] = *(const float4*)&W[(size_t)(t + j * TPB) * 2 * C + c];
#pragma unroll
      for (int kk = 0; kk < K_NBR; ++kk) {
        float4 d = *(const float4*)&diff[kk][c];
#pragma unroll
        for (int j = 0; j < OPT; ++j)
          h[j][kk] += w4[j].x * d.x + w4[j].y * d.y + w4[j].z * d.z + w4[j].w * d.w;
      }
    }
  } else {
    for (int c = 0; c < C; ++c) {
      float wv[OPT];
#pragma unroll
      for (int j = 0; j < OPT; ++j) wv[j] = W[(size_t)(t + j * TPB) * 2 * C + c];
#pragma unroll
      for (int kk = 0; kk < K_NBR; ++kk) {
        float d = diff[kk][c];
#pragma unroll
        for (int j = 0; j < OPT; ++j) h[j][kk] += wv[j] * d;
      }
    }
  }

#pragma unroll
  for (int j = 0; j < OPT; ++j) {
    int o = t + j * TPB;
    float s = 0.f, s2 = 0.f, mx = -__builtin_inff(), mn = __builtin_inff();
#pragma unroll
    for (int kk = 0; kk < K_NBR; ++kk) {
      float v = h[j][kk];
      s += v; s2 += v * v; mx = fmaxf(mx, v); mn = fminf(mn, v);
    }
    atomicAdd(&ssum[o], s);
    atomicAdd(&ssq[o], s2);
    size_t base = ((size_t)b * NPTS + n) * O + o;
    hmax[base] = mx;
    hmin[base] = mn;
  }
}

// ---------------- apply BN(+lrelu) to max (or min if gamma<0), write feats slice ---
__global__ void bn_max_apply_kernel(
    const float* __restrict__ hmax, const float* __restrict__ hmin,
    const float* __restrict__ ssum, const float* __restrict__ ssq,
    const float* __restrict__ g, const float* __restrict__ bt,
    float* __restrict__ feats, int O, int off, float invcnt) {
  int i = blockIdx.x * 256 + threadIdx.x;
  if (i >= NB * NPTS * O) return;
  int r = i / O, o = i - r * O;
  float mean = ssum[o] * invcnt;
  float var = ssq[o] * invcnt - mean * mean;
  float a = g[o] * rsqrtf(var + BN_EPS);
  float h = (a >= 0.f) ? hmax[i] : hmin[i];
  float v = a * (h - mean) + bt[o];
  feats[(size_t)r * 512 + off + o] = lrelu_f(v);
}

// ---------------- global pool: BN+lrelu then max & mean over n (partials) ---------
__global__ void gpool_partial_kernel(
    const float* __restrict__ hglob, const float* __restrict__ ssum,
    const float* __restrict__ ssq, const float* __restrict__ gg,
    const float* __restrict__ bg, float* __restrict__ pmax, float* __restrict__ psum) {
  int b = blockIdx.y;
  int chunk = blockIdx.z;
  int o = blockIdx.x * 256 + threadIdx.x;
  float mean = ssum[o] * (1.f / 8192.f);
  float var = ssq[o] * (1.f / 8192.f) - mean * mean;
  float a = gg[o] * rsqrtf(var + BN_EPS);
  float c0 = bg[o] - a * mean;
  float mx = -__builtin_inff(), sm = 0.f;
  int n0 = chunk * 128;
  for (int n = n0; n < n0 + 128; ++n) {
    float h = hglob[((size_t)b * NPTS + n) * 1024 + o];
    float v = lrelu_f(a * h + c0);
    mx = fmaxf(mx, v);
    sm += v;
  }
  pmax[((size_t)b * 8 + chunk) * 1024 + o] = mx;
  psum[((size_t)b * 8 + chunk) * 1024 + o] = sm;
}

__global__ void gpool_merge_kernel(const float* __restrict__ pmax,
                                   const float* __restrict__ psum, float* __restrict__ z) {
  int i = blockIdx.x * 256 + threadIdx.x;  // 8*1024
  if (i >= NB * 1024) return;
  int b = i >> 10, o = i & 1023;
  float mx = -__builtin_inff(), sm = 0.f;
  for (int chunk = 0; chunk < 8; ++chunk) {
    mx = fmaxf(mx, pmax[((size_t)b * 8 + chunk) * 1024 + o]);
    sm += psum[((size_t)b * 8 + chunk) * 1024 + o];
  }
  z[b * 2048 + o] = mx;
  z[b * 2048 + 1024 + o] = sm * (1.f / 1024.f);
}

// ---------------- FC: out[s,o] = dot(in[s,:], W[o,:]) + bias (one wave per dot) ---
__global__ __launch_bounds__(64) void fc_wave_kernel(
    const float* __restrict__ in, const float* __restrict__ W,
    const float* __restrict__ bias, float* __restrict__ out, int IN, int OUT) {
  int o = blockIdx.x, s = blockIdx.y, t = threadIdx.x;
  const float* x = in + (size_t)s * IN;
  const float* w = W + (size_t)o * IN;
  float acc = 0.f;
  for (int c = t; c < IN; c += 64) acc += x[c] * w[c];
  for (int off = 32; off > 0; off >>= 1) acc += __shfl_down(acc, off);
  if (t == 0) out[(size_t)s * OUT + o] = acc + (bias ? bias[o] : 0.f);
}

// ---------------- BN over batch (8 rows) + lrelu, in place ----------------
__global__ void bn_rows_kernel(float* __restrict__ x, const float* __restrict__ g,
                               const float* __restrict__ bt, int O) {
  int o = blockIdx.x * blockDim.x + threadIdx.x;
  if (o >= O) return;
  float s = 0.f, s2 = 0.f;
#pragma unroll
  for (int r = 0; r < NB; ++r) { float v = x[r * O + o]; s += v; s2 += v * v; }
  float mean = s * 0.125f;
  float var = s2 * 0.125f - mean * mean;
  float a = g[o] * rsqrtf(var + BN_EPS);
  float c0 = bt[o] - a * mean;
#pragma unroll
  for (int r = 0; r < NB; ++r) x[r * O + o] = lrelu_f(a * x[r * O + o] + c0);
}

extern "C" void kernel_launch(void* const* d_in, const int* in_sizes, int n_in,
                              void* d_out, int out_size, void* d_ws, size_t ws_size,
                              hipStream_t stream) {
  const float* x   = (const float*)d_in[0];
  const float* W0  = (const float*)d_in[1];
  const float* g0  = (const float*)d_in[2];
  const float* b0  = (const float*)d_in[3];
  const float* W1  = (const float*)d_in[4];
  const float* g1  = (const float*)d_in[5];
  const float* b1  = (const float*)d_in[6];
  const float* W2  = (const float*)d_in[7];
  const float* g2  = (const float*)d_in[8];
  const float* b2  = (const float*)d_in[9];
  const float* W3  = (const float*)d_in[10];
  const float* g3  = (const float*)d_in[11];
  const float* b3  = (const float*)d_in[12];
  const float* Wg  = (const float*)d_in[13];
  const float* gg  = (const float*)d_in[14];
  const float* bg  = (const float*)d_in[15];
  const float* Wf1 = (const float*)d_in[16];
  const float* gf1 = (const float*)d_in[17];
  const float* bf1 = (const float*)d_in[18];
  const float* Wf2 = (const float*)d_in[19];
  const float* bf2w= (const float*)d_in[20];
  const float* gf2 = (const float*)d_in[21];
  const float* bf2 = (const float*)d_in[22];
  const float* Wf3 = (const float*)d_in[23];
  const float* bf3w= (const float*)d_in[24];
  // d_in[25] = k (==20, hardcoded)

  float* ws = (float*)d_ws;
  float* xt     = ws;                       // 24576
  float* xx     = xt + 24576;               // 8192
  int*   idxb   = (int*)(xx + 8192);        // 163840 ints
  float* feats  = (float*)(idxb + 163840);  // 4194304  [8192][512]
  float* scratch= feats + 4194304;          // 8388608 (dist / hmax+hmin / hglob)
  float* dist   = scratch;
  float* hmax   = scratch;
  float* hmin   = scratch + 2097152;
  float* hglob  = scratch;
  float* stats  = scratch + 8388608;        // 2048
  float* ssum   = stats;
  float* ssq    = stats + 1024;
  float* z      = stats + 2048;             // 16384
  float* pmax   = z + 16384;                // 65536
  float* psum   = pmax + 65536;             // 65536
  float* z2     = psum + 65536;             // 4096
  float* z3     = z2 + 4096;                // 2048
  // total ~12.94M floats (~52 MB) of d_ws

  const float inv_cnt_edge = 1.f / (NB * NPTS * K_NBR);

  // ---- transpose x -> xt
  transpose_kernel<<<dim3(96), dim3(256), 0, stream>>>(x, xt);

  // ================= EdgeConv 1 (xt, C=3, O=64, off=0) =================
  rowsq_kernel<<<dim3(32), dim3(256), 0, stream>>>(xt, 3, 3, xx);
  gemm_nt_kernel<<<dim3(16, 16, 8), dim3(256), 0, stream>>>(
      xt, xt, dist, 1024, 1024, 3, 3, 3, 1024,
      3072L, 3072L, 1048576L, nullptr, nullptr);
  topk_kernel<<<dim3(1024, 8), dim3(256), 0, stream>>>(dist, xx, idxb);
  hipMemsetAsync(stats, 0, 2048 * sizeof(float), stream);
  edgeconv_kernel<3, 64, 64><<<dim3(1024, 8), dim3(64), 0, stream>>>(
      xt, 3, idxb, W0, hmax, hmin, ssum, ssq);
  bn_max_apply_kernel<<<dim3((8192 * 64) / 256), dim3(256), 0, stream>>>(
      hmax, hmin, ssum, ssq, g0, b0, feats, 64, 0, inv_cnt_edge);

  // ================= EdgeConv 2 (f1, C=64, O=64, off=64) =================
  rowsq_kernel<<<dim3(32), dim3(256), 0, stream>>>(feats + 0, 512, 64, xx);
  gemm_nt_kernel<<<dim3(16, 16, 8), dim3(256), 0, stream>>>(
      feats + 0, feats + 0, dist, 1024, 1024, 64, 512, 512, 1024,
      524288L, 524288L, 1048576L, nullptr, nullptr);
  topk_kernel<<<dim3(1024, 8), dim3(256), 0, stream>>>(dist, xx, idxb);
  hipMemsetAsync(stats, 0, 2048 * sizeof(float), stream);
  edgeconv_kernel<64, 64, 64><<<dim3(1024, 8), dim3(64), 0, stream>>>(
      feats + 0, 512, idxb, W1, hmax, hmin, ssum, ssq);
  bn_max_apply_kernel<<<dim3((8192 * 64) / 256), dim3(256), 0, stream>>>(
      hmax, hmin, ssum, ssq, g1, b1, feats, 64, 64, inv_cnt_edge);

  // ================= EdgeConv 3 (f2, C=64, O=128, off=128) =================
  rowsq_kernel<<<dim3(32), dim3(256), 0, stream>>>(feats + 64, 512, 64, xx);
  gemm_nt_kernel<<<dim3(16, 16, 8), dim3(256), 0, stream>>>(
      feats + 64, feats + 64, dist, 1024, 1024, 64, 512, 512, 1024,
      524288L, 524288L, 1048576L, nullptr, nullptr);
  topk_kernel<<<dim3(1024, 8), dim3(256), 0, stream>>>(dist, xx, idxb);
  hipMemsetAsync(stats, 0, 2048 * sizeof(float), stream);
  edgeconv_kernel<64, 128, 64><<<dim3(1024, 8), dim3(64), 0, stream>>>(
      feats + 64, 512, idxb, W2, hmax, hmin, ssum, ssq);
  bn_max_apply_kernel<<<dim3((8192 * 128) / 256), dim3(256), 0, stream>>>(
      hmax, hmin, ssum, ssq, g2, b2, feats, 128, 128, inv_cnt_edge);

  // ================= EdgeConv 4 (f3, C=128, O=256, off=256) =================
  rowsq_kernel<<<dim3(32), dim3(256), 0, stream>>>(feats + 128, 512, 128, xx);
  gemm_nt_kernel<<<dim3(16, 16, 8), dim3(256), 0, stream>>>(
      feats + 128, feats + 128, dist, 1024, 1024, 128, 512, 512, 1024,
      524288L, 524288L, 1048576L, nullptr, nullptr);
  topk_kernel<<<dim3(1024, 8), dim3(256), 0, stream>>>(dist, xx, idxb);
  hipMemsetAsync(stats, 0, 2048 * sizeof(float), stream);
  edgeconv_kernel<128, 256, 128><<<dim3(1024, 8), dim3(128), 0, stream>>>(
      feats + 128, 512, idxb, W3, hmax, hmin, ssum, ssq);
  bn_max_apply_kernel<<<dim3((8192 * 256) / 256), dim3(256), 0, stream>>>(
      hmax, hmin, ssum, ssq, g3, b3, feats, 256, 256, inv_cnt_edge);

  // ================= Global conv (feats @ Wg^T -> hglob) + BN + pool =========
  hipMemsetAsync(stats, 0, 2048 * sizeof(float), stream);
  gemm_nt_kernel<<<dim3(16, 128, 1), dim3(256), 0, stream>>>(
      feats, Wg, hglob, 8192, 1024, 512, 512, 512, 1024,
      0L, 0L, 0L, ssum, ssq);
  gpool_partial_kernel<<<dim3(4, 8, 8), dim3(256), 0, stream>>>(
      hglob, ssum, ssq, gg, bg, pmax, psum);
  gpool_merge_kernel<<<dim3(32), dim3(256), 0, stream>>>(pmax, psum, z);

  // ================= FC head =================
  fc_wave_kernel<<<dim3(512, 8), dim3(64), 0, stream>>>(z, Wf1, nullptr, z2, 2048, 512);
  bn_rows_kernel<<<dim3(2), dim3(256), 0, stream>>>(z2, gf1, bf1, 512);
  fc_wave_kernel<<<dim3(256, 8), dim3(64), 0, stream>>>(z2, Wf2, bf2w, z3, 512, 256);
  bn_rows_kernel<<<dim3(1), dim3(256), 0, stream>>>(z3, gf2, bf2, 256);
  fc_wave_kernel<<<dim3(67, 8), dim3(64), 0, stream>>>(z3, Wf3, bf3w, (float*)d_out, 256, 67);
}

// Round 12
// 1565.879 us; speedup vs baseline: 1.4585x; 1.4585x over previous
//
#include <hip/hip_runtime.h>
#include <math.h>

#define K_NBR 20
#define BN_EPS 1e-5f
#define NPTS 1024
#define NB 8

__device__ __forceinline__ float lrelu_f(float v) { return v >= 0.f ? v : 0.2f * v; }

// ---------------- transpose x [B,3,N] -> xt [B,N,3] ----------------
__global__ void transpose_kernel(const float* __restrict__ x, float* __restrict__ xt) {
  int i = blockIdx.x * 256 + threadIdx.x;
  if (i >= NB * 3 * NPTS) return;
  int b = i / (3 * NPTS);
  int rem = i - b * 3 * NPTS;
  int c = rem / NPTS;
  int n = rem - c * NPTS;
  xt[((size_t)b * NPTS + n) * 3 + c] = x[i];
}

// ---------------- W [O][C2] -> Wt [C2][O] (pure transpose, no value change) ------
__global__ void wtrans_kernel(const float* __restrict__ W, float* __restrict__ Wt,
                              int O, int C2) {
  int i = blockIdx.x * 256 + threadIdx.x;
  if (i >= O * C2) return;
  int o = i / C2, c = i - o * C2;
  Wt[(size_t)c * O + o] = W[i];
}

// ---------------- row squared norms ----------------
__global__ void rowsq_kernel(const float* __restrict__ X, int stride, int C,
                             float* __restrict__ xx) {
  int i = blockIdx.x * 256 + threadIdx.x;
  if (i >= NB * NPTS) return;
  const float* r = X + (size_t)i * stride;
  float s = 0.f;
  for (int c = 0; c < C; ++c) s += r[c] * r[c];
  xx[i] = s;
}

// ---------------- tiled f32 NT-GEMM (64x64 tile): C[r,o]=sum_k A[r,k]*B[o,k] -----
__device__ __forceinline__ float4 load_guard4(const float* __restrict__ rowp, int c, int K) {
  float4 v;
  if (c + 4 <= K) {
    v = *(const float4*)&rowp[c];
  } else {
    v.x = (c + 0 < K) ? rowp[c + 0] : 0.f;
    v.y = (c + 1 < K) ? rowp[c + 1] : 0.f;
    v.z = (c + 2 < K) ? rowp[c + 2] : 0.f;
    v.w = (c + 3 < K) ? rowp[c + 3] : 0.f;
  }
  return v;
}

__global__ __launch_bounds__(256) void gemm_nt_kernel(
    const float* __restrict__ A, const float* __restrict__ B, float* __restrict__ Cm,
    int M, int N, int K, int lda, int ldb, int ldc,
    long batchA, long batchB, long batchC) {
  const float* Ab = A + (size_t)blockIdx.z * batchA;
  const float* Bb = B + (size_t)blockIdx.z * batchB;
  float* Cb = Cm + (size_t)blockIdx.z * batchC;
  __shared__ float As[64][36];
  __shared__ float Bs[64][36];
  int t = threadIdx.x;
  int tx = t & 15, ty = t >> 4;
  int bm = blockIdx.y * 64, bn = blockIdx.x * 64;
  float acc[4][4] = {};
  for (int k0 = 0; k0 < K; k0 += 32) {
#pragma unroll
    for (int i = 0; i < 2; ++i) {
      int li = t * 2 + i;             // 0..511 float4 slots
      int r = li >> 3;
      int c = (li & 7) << 2;
      float4 va = load_guard4(Ab + (size_t)(bm + r) * lda, k0 + c, K);
      As[r][c] = va.x; As[r][c + 1] = va.y; As[r][c + 2] = va.z; As[r][c + 3] = va.w;
      float4 vb = load_guard4(Bb + (size_t)(bn + r) * ldb, k0 + c, K);
      Bs[r][c] = vb.x; Bs[r][c + 1] = vb.y; Bs[r][c + 2] = vb.z; Bs[r][c + 3] = vb.w;
    }
    __syncthreads();
#pragma unroll
    for (int kc = 0; kc < 32; kc += 4) {
      float4 a4[4], b4[4];
#pragma unroll
      for (int i = 0; i < 4; ++i) a4[i] = *(const float4*)&As[ty + 16 * i][kc];
#pragma unroll
      for (int j = 0; j < 4; ++j) b4[j] = *(const float4*)&Bs[tx + 16 * j][kc];
#pragma unroll
      for (int i = 0; i < 4; ++i)
#pragma unroll
        for (int j = 0; j < 4; ++j)
          acc[i][j] += a4[i].x * b4[j].x + a4[i].y * b4[j].y +
                       a4[i].z * b4[j].z + a4[i].w * b4[j].w;
    }
    __syncthreads();
  }
#pragma unroll
  for (int i = 0; i < 4; ++i) {
    int r = bm + ty + 16 * i;
#pragma unroll
    for (int j = 0; j < 4; ++j) {
      int o = bn + tx + 16 * j;
      Cb[(size_t)r * ldc + o] = acc[i][j];
    }
  }
}

// ---------------- top-k (k=20), validated 256-thread LDS version ------------------
__global__ __launch_bounds__(256) void topk_kernel(
    const float* __restrict__ inner, const float* __restrict__ xx, int* __restrict__ idxb) {
  int b = blockIdx.y, n = blockIdx.x, t = threadIdx.x;
  __shared__ float nd[NPTS];
  __shared__ float rv[256];
  __shared__ int ri[256];
  float xxn = xx[b * NPTS + n];
  const float* row = inner + ((size_t)b * NPTS + n) * NPTS;
  for (int m = t; m < NPTS; m += 256)
    nd[m] = 2.f * row[m] - xxn - xx[b * NPTS + m];
  __syncthreads();
  for (int kk = 0; kk < K_NBR; ++kk) {
    float bv = -__builtin_inff(); int bi = NPTS;
    for (int m = t; m < NPTS; m += 256) {
      float v = nd[m];
      if (v > bv || (v == bv && m < bi)) { bv = v; bi = m; }
    }
    rv[t] = bv; ri[t] = bi;
    __syncthreads();
    for (int s = 128; s > 0; s >>= 1) {
      if (t < s) {
        float ov = rv[t + s]; int oi = ri[t + s];
        if (ov > rv[t] || (ov == rv[t] && oi < ri[t])) { rv[t] = ov; ri[t] = oi; }
      }
      __syncthreads();
    }
    if (t == 0) {
      idxb[((size_t)b * NPTS + n) * K_NBR + kk] = ri[0];
      nd[ri[0]] = -__builtin_inff();
    }
    __syncthreads();
  }
}

// ---------------- edge conv (direct, round-2 arithmetic), P points per block ------
// Per (point,o): h[k] = sum_c Wc[o][c]*center[c]  (ascending c)
//                      + sum_{c chunks} Wd[o][c..c+3] . diff[k][c..c+3]
// Identical association to the validated round-2 kernel. NO atomics: per-point
// sum/sumsq are stored to sarr/s2arr for a deterministic reduction afterwards.
template <int C, int O, int P>
__global__ __launch_bounds__(O) void edgeconv2_kernel(
    const float* __restrict__ X, int stride, const int* __restrict__ idxb,
    const float* __restrict__ Wt, float* __restrict__ hmax, float* __restrict__ hmin,
    float* __restrict__ sarr, float* __restrict__ s2arr) {
  constexpr int TPB = O;
  int t = threadIdx.x;
  int p0 = blockIdx.x * P;                    // global point ids p0..p0+P-1
  __shared__ float center[P][C];
  __shared__ float diff[P][K_NBR][C];
  __shared__ int sidx[P][K_NBR];
  for (int i = t; i < P * C; i += TPB) {
    int p = i / C, c = i - p * C;
    center[p][c] = X[(size_t)(p0 + p) * stride + c];
  }
  if (t < P * K_NBR) {
    int p = t / K_NBR, k = t - p * K_NBR;
    sidx[p][k] = idxb[(size_t)(p0 + p) * K_NBR + k];
  }
  __syncthreads();
  for (int i = t; i < P * K_NBR * C; i += TPB) {
    int p = i / (K_NBR * C);
    int rem = i - p * (K_NBR * C);
    int kk = rem / C, c = rem - kk * C;
    int bbase = ((p0 + p) >> 10) << 10;
    diff[p][kk][c] = X[(size_t)(bbase + sidx[p][kk]) * stride + c] - center[p][c];
  }
  __syncthreads();

  int o = t;
  float h[P][K_NBR];
  // init with Wc . center (ascending c, per point)
  {
    float wc[P];
#pragma unroll
    for (int p = 0; p < P; ++p) wc[p] = 0.f;
    for (int c = 0; c < C; ++c) {
      float wv = Wt[(size_t)(C + c) * O + o];
#pragma unroll
      for (int p = 0; p < P; ++p) wc[p] += wv * center[p][c];
    }
#pragma unroll
    for (int p = 0; p < P; ++p)
#pragma unroll
      for (int kk = 0; kk < K_NBR; ++kk) h[p][kk] = wc[p];
  }

  if constexpr (C % 4 == 0) {
    for (int c = 0; c < C; c += 4) {
      float w0 = Wt[(size_t)(c + 0) * O + o];
      float w1 = Wt[(size_t)(c + 1) * O + o];
      float w2 = Wt[(size_t)(c + 2) * O + o];
      float w3 = Wt[(size_t)(c + 3) * O + o];
#pragma unroll
      for (int p = 0; p < P; ++p)
#pragma unroll
        for (int kk = 0; kk < K_NBR; ++kk) {
          float4 d = *(const float4*)&diff[p][kk][c];
          h[p][kk] += w0 * d.x + w1 * d.y + w2 * d.z + w3 * d.w;
        }
    }
  } else {
    for (int c = 0; c < C; ++c) {
      float wv = Wt[(size_t)c * O + o];
#pragma unroll
      for (int p = 0; p < P; ++p)
#pragma unroll
        for (int kk = 0; kk < K_NBR; ++kk) h[p][kk] += wv * diff[p][kk][c];
    }
  }

#pragma unroll
  for (int p = 0; p < P; ++p) {
    float s = 0.f, s2 = 0.f, mx = -__builtin_inff(), mn = __builtin_inff();
#pragma unroll
    for (int kk = 0; kk < K_NBR; ++kk) {
      float v = h[p][kk];
      s += v; s2 += v * v; mx = fmaxf(mx, v); mn = fminf(mn, v);
    }
    size_t base = (size_t)(p0 + p) * O + o;
    hmax[base] = mx;
    hmin[base] = mn;
    sarr[base] = s;
    s2arr[base] = s2;
  }
}

// ---------------- deterministic column reductions (fixed order, no atomics) -------
// A, A2: [8192][O] per-point sum and sumsq. 32 chunks x 256 points each.
__global__ void colsum_partial_kernel(const float* __restrict__ A,
                                      const float* __restrict__ A2,
                                      float* __restrict__ ps, float* __restrict__ ps2,
                                      int O) {
  int o = blockIdx.x * 256 + threadIdx.x;
  if (o >= O) return;
  int p0 = blockIdx.y * 256;
  float s = 0.f, s2 = 0.f;
  for (int p = p0; p < p0 + 256; ++p) {
    s += A[(size_t)p * O + o];
    s2 += A2[(size_t)p * O + o];
  }
  ps[(size_t)blockIdx.y * O + o] = s;
  ps2[(size_t)blockIdx.y * O + o] = s2;
}

// A: [8192][O] raw values; computes per-chunk sum and sum of squares.
__global__ void colsumsq_partial_kernel(const float* __restrict__ A,
                                        float* __restrict__ ps, float* __restrict__ ps2,
                                        int O) {
  int o = blockIdx.x * 256 + threadIdx.x;
  if (o >= O) return;
  int p0 = blockIdx.y * 256;
  float s = 0.f, s2 = 0.f;
  for (int p = p0; p < p0 + 256; ++p) {
    float v = A[(size_t)p * O + o];
    s += v; s2 += v * v;
  }
  ps[(size_t)blockIdx.y * O + o] = s;
  ps2[(size_t)blockIdx.y * O + o] = s2;
}

__global__ void colsum_final_kernel(const float* __restrict__ ps,
                                    const float* __restrict__ ps2,
                                    float* __restrict__ ssum, float* __restrict__ ssq,
                                    int O) {
  int o = blockIdx.x * 256 + threadIdx.x;
  if (o >= O) return;
  float s = 0.f, s2 = 0.f;
  for (int c = 0; c < 32; ++c) {
    s += ps[(size_t)c * O + o];
    s2 += ps2[(size_t)c * O + o];
  }
  ssum[o] = s;
  ssq[o] = s2;
}

// ---------------- apply BN(+lrelu) to max (or min if gamma<0), write feats slice --
__global__ void bn_max_apply_kernel(
    const float* __restrict__ hmax, const float* __restrict__ hmin,
    const float* __restrict__ ssum, const float* __restrict__ ssq,
    const float* __restrict__ g, const float* __restrict__ bt,
    float* __restrict__ feats, int O, int off, float invcnt) {
  int i = blockIdx.x * 256 + threadIdx.x;
  if (i >= NB * NPTS * O) return;
  int r = i / O, o = i - r * O;
  float mean = ssum[o] * invcnt;
  float var = ssq[o] * invcnt - mean * mean;
  float a = g[o] * rsqrtf(var + BN_EPS);
  float h = (a >= 0.f) ? hmax[i] : hmin[i];
  float v = a * (h - mean) + bt[o];
  feats[(size_t)r * 512 + off + o] = lrelu_f(v);
}

// ---------------- global pool: BN+lrelu then max & mean over n (partials) ---------
__global__ void gpool_partial_kernel(
    const float* __restrict__ hglob, const float* __restrict__ ssum,
    const float* __restrict__ ssq, const float* __restrict__ gg,
    const float* __restrict__ bg, float* __restrict__ pmax, float* __restrict__ psum) {
  int b = blockIdx.y;
  int chunk = blockIdx.z;
  int o = blockIdx.x * 256 + threadIdx.x;
  float mean = ssum[o] * (1.f / 8192.f);
  float var = ssq[o] * (1.f / 8192.f) - mean * mean;
  float a = gg[o] * rsqrtf(var + BN_EPS);
  float c0 = bg[o] - a * mean;
  float mx = -__builtin_inff(), sm = 0.f;
  int n0 = chunk * 128;
  for (int n = n0; n < n0 + 128; ++n) {
    float h = hglob[((size_t)b * NPTS + n) * 1024 + o];
    float v = lrelu_f(a * h + c0);
    mx = fmaxf(mx, v);
    sm += v;
  }
  pmax[((size_t)b * 8 + chunk) * 1024 + o] = mx;
  psum[((size_t)b * 8 + chunk) * 1024 + o] = sm;
}

__global__ void gpool_merge_kernel(const float* __restrict__ pmax,
                                   const float* __restrict__ psum, float* __restrict__ z) {
  int i = blockIdx.x * 256 + threadIdx.x;  // 8*1024
  if (i >= NB * 1024) return;
  int b = i >> 10, o = i & 1023;
  float mx = -__builtin_inff(), sm = 0.f;
  for (int chunk = 0; chunk < 8; ++chunk) {
    mx = fmaxf(mx, pmax[((size_t)b * 8 + chunk) * 1024 + o]);
    sm += psum[((size_t)b * 8 + chunk) * 1024 + o];
  }
  z[b * 2048 + o] = mx;
  z[b * 2048 + 1024 + o] = sm * (1.f / 1024.f);
}

// ---------------- FC: out[s,o] = dot(in[s,:], W[o,:]) + bias (one wave per dot) ---
__global__ __launch_bounds__(64) void fc_wave_kernel(
    const float* __restrict__ in, const float* __restrict__ W,
    const float* __restrict__ bias, float* __restrict__ out, int IN, int OUT) {
  int o = blockIdx.x, s = blockIdx.y, t = threadIdx.x;
  const float* x = in + (size_t)s * IN;
  const float* w = W + (size_t)o * IN;
  float acc = 0.f;
  for (int c = t; c < IN; c += 64) acc += x[c] * w[c];
  for (int off = 32; off > 0; off >>= 1) acc += __shfl_down(acc, off);
  if (t == 0) out[(size_t)s * OUT + o] = acc + (bias ? bias[o] : 0.f);
}

// ---------------- BN over batch (8 rows) + lrelu, in place ----------------
__global__ void bn_rows_kernel(float* __restrict__ x, const float* __restrict__ g,
                               const float* __restrict__ bt, int O) {
  int o = blockIdx.x * blockDim.x + threadIdx.x;
  if (o >= O) return;
  float s = 0.f, s2 = 0.f;
#pragma unroll
  for (int r = 0; r < NB; ++r) { float v = x[r * O + o]; s += v; s2 += v * v; }
  float mean = s * 0.125f;
  float var = s2 * 0.125f - mean * mean;
  float a = g[o] * rsqrtf(var + BN_EPS);
  float c0 = bt[o] - a * mean;
#pragma unroll
  for (int r = 0; r < NB; ++r) x[r * O + o] = lrelu_f(a * x[r * O + o] + c0);
}

extern "C" void kernel_launch(void* const* d_in, const int* in_sizes, int n_in,
                              void* d_out, int out_size, void* d_ws, size_t ws_size,
                              hipStream_t stream) {
  const float* x   = (const float*)d_in[0];
  const float* W0  = (const float*)d_in[1];
  const float* g0  = (const float*)d_in[2];
  const float* b0  = (const float*)d_in[3];
  const float* W1  = (const float*)d_in[4];
  const float* g1  = (const float*)d_in[5];
  const float* b1  = (const float*)d_in[6];
  const float* W2  = (const float*)d_in[7];
  const float* g2  = (const float*)d_in[8];
  const float* b2  = (const float*)d_in[9];
  const float* W3  = (const float*)d_in[10];
  const float* g3  = (const float*)d_in[11];
  const float* b3  = (const float*)d_in[12];
  const float* Wg  = (const float*)d_in[13];
  const float* gg  = (const float*)d_in[14];
  const float* bg  = (const float*)d_in[15];
  const float* Wf1 = (const float*)d_in[16];
  const float* gf1 = (const float*)d_in[17];
  const float* bf1 = (const float*)d_in[18];
  const float* Wf2 = (const float*)d_in[19];
  const float* bf2w= (const float*)d_in[20];
  const float* gf2 = (const float*)d_in[21];
  const float* bf2 = (const float*)d_in[22];
  const float* Wf3 = (const float*)d_in[23];
  const float* bf3w= (const float*)d_in[24];
  // d_in[25] = k (==20, hardcoded)

  float* ws = (float*)d_ws;
  float* xt     = ws;                       // 24576
  float* xx     = xt + 24576;               // 8192
  int*   idxb   = (int*)(xx + 8192);        // 163840 ints
  float* feats  = (float*)(idxb + 163840);  // 4194304  [8192][512]
  float* scratch= feats + 4194304;          // 8388608 (dist | hmax+hmin+sarr+s2arr | hglob)
  float* dist   = scratch;
  float* hmax   = scratch;                  // [8192][O] <= 2M
  float* hmin   = scratch + 2097152;
  float* sarr   = scratch + 4194304;
  float* s2arr  = scratch + 6291456;
  float* hglob  = scratch;                  // [8192][1024] for gconv
  float* stats  = scratch + 8388608;        // 2048
  float* ssum   = stats;
  float* ssq    = stats + 1024;
  float* z      = stats + 2048;             // 16384
  float* pmax   = z + 16384;                // 65536
  float* psum   = pmax + 65536;             // 65536
  float* z2     = psum + 65536;             // 4096
  float* z3     = z2 + 4096;                // 2048
  float* wt0    = z3 + 2048;                // 384   (Wt: [2C][O])
  float* wt1    = wt0 + 384;                // 8192
  float* wt2    = wt1 + 8192;               // 16384
  float* wt3    = wt2 + 16384;              // 65536
  // Deterministic-reduction partials, aliased into serially-disjoint regions:
  float* part_s  = z;                       // 32*O <= 8192 (consumed before gpool_merge writes z)
  float* part_s2 = z + 8192;
  float* gpart_s  = pmax;                   // 32*1024 (consumed before gpool_partial writes pmax)
  float* gpart_s2 = psum;
  // total ~13.03M floats (~52.1 MB), same as round 11 (eager-proven in bounds)

  const float inv_cnt_edge = 1.f / (NB * NPTS * K_NBR);

  // ---- transpose x -> xt; transpose weights (pure data movement)
  transpose_kernel<<<dim3(96), dim3(256), 0, stream>>>(x, xt);
  wtrans_kernel<<<dim3(2),   dim3(256), 0, stream>>>(W0, wt0, 64, 6);
  wtrans_kernel<<<dim3(32),  dim3(256), 0, stream>>>(W1, wt1, 64, 128);
  wtrans_kernel<<<dim3(64),  dim3(256), 0, stream>>>(W2, wt2, 128, 128);
  wtrans_kernel<<<dim3(256), dim3(256), 0, stream>>>(W3, wt3, 256, 256);

  // ================= EdgeConv 1 (xt, C=3, O=64, off=0) =================
  rowsq_kernel<<<dim3(32), dim3(256), 0, stream>>>(xt, 3, 3, xx);
  gemm_nt_kernel<<<dim3(16, 16, 8), dim3(256), 0, stream>>>(
      xt, xt, dist, 1024, 1024, 3, 3, 3, 1024, 3072L, 3072L, 1048576L);
  topk_kernel<<<dim3(1024, 8), dim3(256), 0, stream>>>(dist, xx, idxb);
  edgeconv2_kernel<3, 64, 2><<<dim3(4096), dim3(64), 0, stream>>>(
      xt, 3, idxb, wt0, hmax, hmin, sarr, s2arr);
  colsum_partial_kernel<<<dim3(1, 32), dim3(256), 0, stream>>>(sarr, s2arr, part_s, part_s2, 64);
  colsum_final_kernel<<<dim3(1), dim3(256), 0, stream>>>(part_s, part_s2, ssum, ssq, 64);
  bn_max_apply_kernel<<<dim3((8192 * 64) / 256), dim3(256), 0, stream>>>(
      hmax, hmin, ssum, ssq, g0, b0, feats, 64, 0, inv_cnt_edge);

  // ================= EdgeConv 2 (f1, C=64, O=64, off=64) =================
  rowsq_kernel<<<dim3(32), dim3(256), 0, stream>>>(feats + 0, 512, 64, xx);
  gemm_nt_kernel<<<dim3(16, 16, 8), dim3(256), 0, stream>>>(
      feats + 0, feats + 0, dist, 1024, 1024, 64, 512, 512, 1024,
      524288L, 524288L, 1048576L);
  topk_kernel<<<dim3(1024, 8), dim3(256), 0, stream>>>(dist, xx, idxb);
  edgeconv2_kernel<64, 64, 2><<<dim3(4096), dim3(64), 0, stream>>>(
      feats + 0, 512, idxb, wt1, hmax, hmin, sarr, s2arr);
  colsum_partial_kernel<<<dim3(1, 32), dim3(256), 0, stream>>>(sarr, s2arr, part_s, part_s2, 64);
  colsum_final_kernel<<<dim3(1), dim3(256), 0, stream>>>(part_s, part_s2, ssum, ssq, 64);
  bn_max_apply_kernel<<<dim3((8192 * 64) / 256), dim3(256), 0, stream>>>(
      hmax, hmin, ssum, ssq, g1, b1, feats, 64, 64, inv_cnt_edge);

  // ================= EdgeConv 3 (f2, C=64, O=128, off=128) =================
  rowsq_kernel<<<dim3(32), dim3(256), 0, stream>>>(feats + 64, 512, 64, xx);
  gemm_nt_kernel<<<dim3(16, 16, 8), dim3(256), 0, stream>>>(
      feats + 64, feats + 64, dist, 1024, 1024, 64, 512, 512, 1024,
      524288L, 524288L, 1048576L);
  topk_kernel<<<dim3(1024, 8), dim3(256), 0, stream>>>(dist, xx, idxb);
  edgeconv2_kernel<64, 128, 2><<<dim3(4096), dim3(128), 0, stream>>>(
      feats + 64, 512, idxb, wt2, hmax, hmin, sarr, s2arr);
  colsum_partial_kernel<<<dim3(1, 32), dim3(256), 0, stream>>>(sarr, s2arr, part_s, part_s2, 128);
  colsum_final_kernel<<<dim3(1), dim3(256), 0, stream>>>(part_s, part_s2, ssum, ssq, 128);
  bn_max_apply_kernel<<<dim3((8192 * 128) / 256), dim3(256), 0, stream>>>(
      hmax, hmin, ssum, ssq, g2, b2, feats, 128, 128, inv_cnt_edge);

  // ================= EdgeConv 4 (f3, C=128, O=256, off=256) =================
  rowsq_kernel<<<dim3(32), dim3(256), 0, stream>>>(feats + 128, 512, 128, xx);
  gemm_nt_kernel<<<dim3(16, 16, 8), dim3(256), 0, stream>>>(
      feats + 128, feats + 128, dist, 1024, 1024, 128, 512, 512, 1024,
      524288L, 524288L, 1048576L);
  topk_kernel<<<dim3(1024, 8), dim3(256), 0, stream>>>(dist, xx, idxb);
  edgeconv2_kernel<128, 256, 2><<<dim3(4096), dim3(256), 0, stream>>>(
      feats + 128, 512, idxb, wt3, hmax, hmin, sarr, s2arr);
  colsum_partial_kernel<<<dim3(1, 32), dim3(256), 0, stream>>>(sarr, s2arr, part_s, part_s2, 256);
  colsum_final_kernel<<<dim3(1), dim3(256), 0, stream>>>(part_s, part_s2, ssum, ssq, 256);
  bn_max_apply_kernel<<<dim3((8192 * 256) / 256), dim3(256), 0, stream>>>(
      hmax, hmin, ssum, ssq, g3, b3, feats, 256, 256, inv_cnt_edge);

  // ================= Global conv (feats @ Wg^T -> hglob) + BN + pool =========
  gemm_nt_kernel<<<dim3(16, 128, 1), dim3(256), 0, stream>>>(
      feats, Wg, hglob, 8192, 1024, 512, 512, 512, 1024, 0L, 0L, 0L);
  colsumsq_partial_kernel<<<dim3(4, 32), dim3(256), 0, stream>>>(hglob, gpart_s, gpart_s2, 1024);
  colsum_final_kernel<<<dim3(4), dim3(256), 0, stream>>>(gpart_s, gpart_s2, ssum, ssq, 1024);
  gpool_partial_kernel<<<dim3(4, 8, 8), dim3(256), 0, stream>>>(
      hglob, ssum, ssq, gg, bg, pmax, psum);
  gpool_merge_kernel<<<dim3(32), dim3(256), 0, stream>>>(pmax, psum, z);

  // ================= FC head =================
  fc_wave_kernel<<<dim3(512, 8), dim3(64), 0, stream>>>(z, Wf1, nullptr, z2, 2048, 512);
  bn_rows_kernel<<<dim3(2), dim3(256), 0, stream>>>(z2, gf1, bf1, 512);
  fc_wave_kernel<<<dim3(256, 8), dim3(64), 0, stream>>>(z2, Wf2, bf2w, z3, 512, 256);
  bn_rows_kernel<<<dim3(1), dim3(256), 0, stream>>>(z3, gf2, bf2, 256);
  fc_wave_kernel<<<dim3(67, 8), dim3(64), 0, stream>>>(z3, Wf3, bf3w, (float*)d_out, 256, 67);
}

// Round 13
// 1554.426 us; speedup vs baseline: 1.4692x; 1.0074x over previous
//
#include <hip/hip_runtime.h>
#include <math.h>

#define K_NBR 20
#define BN_EPS 1e-5f
#define NPTS 1024
#define NB 8

__device__ __forceinline__ float lrelu_f(float v) { return v >= 0.f ? v : 0.2f * v; }

// ---------------- transpose x [B,3,N] -> xt [B,N,3] ----------------
__global__ void transpose_kernel(const float* __restrict__ x, float* __restrict__ xt) {
  int i = blockIdx.x * 256 + threadIdx.x;
  if (i >= NB * 3 * NPTS) return;
  int b = i / (3 * NPTS);
  int rem = i - b * 3 * NPTS;
  int c = rem / NPTS;
  int n = rem - c * NPTS;
  xt[((size_t)b * NPTS + n) * 3 + c] = x[i];
}

// ---------------- W [O][C2] -> Wt [C2][O] (pure transpose, no value change) ------
__global__ void wtrans_kernel(const float* __restrict__ W, float* __restrict__ Wt,
                              int O, int C2) {
  int i = blockIdx.x * 256 + threadIdx.x;
  if (i >= O * C2) return;
  int o = i / C2, c = i - o * C2;
  Wt[(size_t)c * O + o] = W[i];
}

// ---------------- row squared norms ----------------
__global__ void rowsq_kernel(const float* __restrict__ X, int stride, int C,
                             float* __restrict__ xx) {
  int i = blockIdx.x * 256 + threadIdx.x;
  if (i >= NB * NPTS) return;
  const float* r = X + (size_t)i * stride;
  float s = 0.f;
  for (int c = 0; c < C; ++c) s += r[c] * r[c];
  xx[i] = s;
}

// ---------------- tiled f32 NT-GEMM (64x64 tile): C[r,o]=sum_k A[r,k]*B[o,k] -----
__device__ __forceinline__ float4 load_guard4(const float* __restrict__ rowp, int c, int K) {
  float4 v;
  if (c + 4 <= K) {
    v = *(const float4*)&rowp[c];
  } else {
    v.x = (c + 0 < K) ? rowp[c + 0] : 0.f;
    v.y = (c + 1 < K) ? rowp[c + 1] : 0.f;
    v.z = (c + 2 < K) ? rowp[c + 2] : 0.f;
    v.w = (c + 3 < K) ? rowp[c + 3] : 0.f;
  }
  return v;
}

__global__ __launch_bounds__(256) void gemm_nt_kernel(
    const float* __restrict__ A, const float* __restrict__ B, float* __restrict__ Cm,
    int M, int N, int K, int lda, int ldb, int ldc,
    long batchA, long batchB, long batchC) {
  const float* Ab = A + (size_t)blockIdx.z * batchA;
  const float* Bb = B + (size_t)blockIdx.z * batchB;
  float* Cb = Cm + (size_t)blockIdx.z * batchC;
  __shared__ float As[64][36];
  __shared__ float Bs[64][36];
  int t = threadIdx.x;
  int tx = t & 15, ty = t >> 4;
  int bm = blockIdx.y * 64, bn = blockIdx.x * 64;
  float acc[4][4] = {};
  for (int k0 = 0; k0 < K; k0 += 32) {
#pragma unroll
    for (int i = 0; i < 2; ++i) {
      int li = t * 2 + i;             // 0..511 float4 slots
      int r = li >> 3;
      int c = (li & 7) << 2;
      float4 va = load_guard4(Ab + (size_t)(bm + r) * lda, k0 + c, K);
      As[r][c] = va.x; As[r][c + 1] = va.y; As[r][c + 2] = va.z; As[r][c + 3] = va.w;
      float4 vb = load_guard4(Bb + (size_t)(bn + r) * ldb, k0 + c, K);
      Bs[r][c] = vb.x; Bs[r][c + 1] = vb.y; Bs[r][c + 2] = vb.z; Bs[r][c + 3] = vb.w;
    }
    __syncthreads();
#pragma unroll
    for (int kc = 0; kc < 32; kc += 4) {
      float4 a4[4], b4[4];
#pragma unroll
      for (int i = 0; i < 4; ++i) a4[i] = *(const float4*)&As[ty + 16 * i][kc];
#pragma unroll
      for (int j = 0; j < 4; ++j) b4[j] = *(const float4*)&Bs[tx + 16 * j][kc];
#pragma unroll
      for (int i = 0; i < 4; ++i)
#pragma unroll
        for (int j = 0; j < 4; ++j)
          acc[i][j] += a4[i].x * b4[j].x + a4[i].y * b4[j].y +
                       a4[i].z * b4[j].z + a4[i].w * b4[j].w;
    }
    __syncthreads();
  }
#pragma unroll
  for (int i = 0; i < 4; ++i) {
    int r = bm + ty + 16 * i;
#pragma unroll
    for (int j = 0; j < 4; ++j) {
      int o = bn + tx + 16 * j;
      Cb[(size_t)r * ldc + o] = acc[i][j];
    }
  }
}

// ---------------- top-k (k=20), validated 256-thread LDS version ------------------
__global__ __launch_bounds__(256) void topk_kernel(
    const float* __restrict__ inner, const float* __restrict__ xx, int* __restrict__ idxb) {
  int b = blockIdx.y, n = blockIdx.x, t = threadIdx.x;
  __shared__ float nd[NPTS];
  __shared__ float rv[256];
  __shared__ int ri[256];
  float xxn = xx[b * NPTS + n];
  const float* row = inner + ((size_t)b * NPTS + n) * NPTS;
  for (int m = t; m < NPTS; m += 256)
    nd[m] = 2.f * row[m] - xxn - xx[b * NPTS + m];
  __syncthreads();
  for (int kk = 0; kk < K_NBR; ++kk) {
    float bv = -__builtin_inff(); int bi = NPTS;
    for (int m = t; m < NPTS; m += 256) {
      float v = nd[m];
      if (v > bv || (v == bv && m < bi)) { bv = v; bi = m; }
    }
    rv[t] = bv; ri[t] = bi;
    __syncthreads();
    for (int s = 128; s > 0; s >>= 1) {
      if (t < s) {
        float ov = rv[t + s]; int oi = ri[t + s];
        if (ov > rv[t] || (ov == rv[t] && oi < ri[t])) { rv[t] = ov; ri[t] = oi; }
      }
      __syncthreads();
    }
    if (t == 0) {
      idxb[((size_t)b * NPTS + n) * K_NBR + kk] = ri[0];
      nd[ri[0]] = -__builtin_inff();
    }
    __syncthreads();
  }
}

// ---------------- edge conv (round-2 arithmetic), small-P version for C=3 ---------
template <int C, int O, int P>
__global__ __launch_bounds__(O) void edgeconv2_kernel(
    const float* __restrict__ X, int stride, const int* __restrict__ idxb,
    const float* __restrict__ Wt, float* __restrict__ hmax, float* __restrict__ hmin,
    float* __restrict__ sarr, float* __restrict__ s2arr) {
  constexpr int TPB = O;
  int t = threadIdx.x;
  int p0 = blockIdx.x * P;
  __shared__ float center[P][C];
  __shared__ float diff[P][K_NBR][C];
  __shared__ int sidx[P][K_NBR];
  for (int i = t; i < P * C; i += TPB) {
    int p = i / C, c = i - p * C;
    center[p][c] = X[(size_t)(p0 + p) * stride + c];
  }
  if (t < P * K_NBR) {
    int p = t / K_NBR, k = t - p * K_NBR;
    sidx[p][k] = idxb[(size_t)(p0 + p) * K_NBR + k];
  }
  __syncthreads();
  for (int i = t; i < P * K_NBR * C; i += TPB) {
    int p = i / (K_NBR * C);
    int rem = i - p * (K_NBR * C);
    int kk = rem / C, c = rem - kk * C;
    int bbase = ((p0 + p) >> 10) << 10;
    diff[p][kk][c] = X[(size_t)(bbase + sidx[p][kk]) * stride + c] - center[p][c];
  }
  __syncthreads();

  int o = t;
  float h[P][K_NBR];
  {
    float wc[P];
#pragma unroll
    for (int p = 0; p < P; ++p) wc[p] = 0.f;
    for (int c = 0; c < C; ++c) {
      float wv = Wt[(size_t)(C + c) * O + o];
#pragma unroll
      for (int p = 0; p < P; ++p) wc[p] += wv * center[p][c];
    }
#pragma unroll
    for (int p = 0; p < P; ++p)
#pragma unroll
      for (int kk = 0; kk < K_NBR; ++kk) h[p][kk] = wc[p];
  }

  if constexpr (C % 4 == 0) {
    for (int c = 0; c < C; c += 4) {
      float w0 = Wt[(size_t)(c + 0) * O + o];
      float w1 = Wt[(size_t)(c + 1) * O + o];
      float w2 = Wt[(size_t)(c + 2) * O + o];
      float w3 = Wt[(size_t)(c + 3) * O + o];
#pragma unroll
      for (int p = 0; p < P; ++p)
#pragma unroll
        for (int kk = 0; kk < K_NBR; ++kk) {
          float4 d = *(const float4*)&diff[p][kk][c];
          h[p][kk] += w0 * d.x + w1 * d.y + w2 * d.z + w3 * d.w;
        }
    }
  } else {
    for (int c = 0; c < C; ++c) {
      float wv = Wt[(size_t)c * O + o];
#pragma unroll
      for (int p = 0; p < P; ++p)
#pragma unroll
        for (int kk = 0; kk < K_NBR; ++kk) h[p][kk] += wv * diff[p][kk][c];
    }
  }

#pragma unroll
  for (int p = 0; p < P; ++p) {
    float s = 0.f, s2 = 0.f, mx = -__builtin_inff(), mn = __builtin_inff();
#pragma unroll
    for (int kk = 0; kk < K_NBR; ++kk) {
      float v = h[p][kk];
      s += v; s2 += v * v; mx = fmaxf(mx, v); mn = fminf(mn, v);
    }
    size_t base = (size_t)(p0 + p) * O + o;
    hmax[base] = mx;
    hmin[base] = mn;
    sarr[base] = s;
    s2arr[base] = s2;
  }
}

// ---------------- register-tiled edge conv: thread = 5 kk x 4 o tile --------------
// Per-chunk update expression is BIT-IDENTICAL to edgeconv2's C%4==0 path:
//   h += w0*d.x + w1*d.y + w2*d.z + w3*d.w   (ascending 4-channel chunks)
// wc init identical (ascending c scalar). Only the cross-kt s/s2 combine
// reassociates (max/min are exact under reassociation).
template <int C, int O>
__global__ __launch_bounds__(256) void edgeconv3_kernel(
    const float* __restrict__ X, int stride, const int* __restrict__ idxb,
    const float* __restrict__ Wt, float* __restrict__ hmax, float* __restrict__ hmin,
    float* __restrict__ sarr, float* __restrict__ s2arr) {
  constexpr int PPB = 256 / O;        // points per block (1,2,4)
  constexpr int OT = O / 4;           // o-tiles per point
  int t = threadIdx.x;
  int p0 = blockIdx.x * PPB;
  __shared__ float center[PPB][C];
  __shared__ float diff[PPB][K_NBR][C];
  __shared__ int sidx[PPB][K_NBR];
  __shared__ float wcs[256];
  __shared__ float redm[1024], redn[1024], reds[1024], reds2[1024];

  for (int i = t; i < PPB * C; i += 256) {
    int p = i / C, c = i - p * C;
    center[p][c] = X[(size_t)(p0 + p) * stride + c];
  }
  if (t < PPB * K_NBR) {
    int p = t / K_NBR, k = t - p * K_NBR;
    sidx[p][k] = idxb[(size_t)(p0 + p) * K_NBR + k];
  }
  __syncthreads();
  for (int i = t; i < PPB * K_NBR * C; i += 256) {
    int p = i / (K_NBR * C);
    int rem = i - p * (K_NBR * C);
    int kk = rem / C, c = rem - kk * C;
    int bbase = ((p0 + p) >> 10) << 10;
    diff[p][kk][c] = X[(size_t)(bbase + sidx[p][kk]) * stride + c] - center[p][c];
  }
  {
    // wc for (p = t/O, o = t%O): ascending-c scalar association (same as edgeconv2)
    int p = t / O, o = t - (t / O) * O;
    float acc = 0.f;
    for (int c = 0; c < C; ++c) acc += Wt[(size_t)(C + c) * O + o] * center[p][c];
    wcs[t] = acc;
  }
  __syncthreads();

  int p = t / O;
  int tid = t - p * O;
  int kt = tid / OT;
  int ot = tid - kt * OT;
  int ob = ot * 4;

  float h[5][4];
#pragma unroll
  for (int j = 0; j < 5; ++j)
#pragma unroll
    for (int i = 0; i < 4; ++i) h[j][i] = wcs[p * O + ob + i];

  for (int c = 0; c < C; c += 4) {
    float4 w0 = *(const float4*)&Wt[(size_t)(c + 0) * O + ob];
    float4 w1 = *(const float4*)&Wt[(size_t)(c + 1) * O + ob];
    float4 w2 = *(const float4*)&Wt[(size_t)(c + 2) * O + ob];
    float4 w3 = *(const float4*)&Wt[(size_t)(c + 3) * O + ob];
#pragma unroll
    for (int j = 0; j < 5; ++j) {
      float4 d = *(const float4*)&diff[p][kt * 5 + j][c];
      h[j][0] += w0.x * d.x + w1.x * d.y + w2.x * d.z + w3.x * d.w;
      h[j][1] += w0.y * d.x + w1.y * d.y + w2.y * d.z + w3.y * d.w;
      h[j][2] += w0.z * d.x + w1.z * d.y + w2.z * d.z + w3.z * d.w;
      h[j][3] += w0.w * d.x + w1.w * d.y + w2.w * d.z + w3.w * d.w;
    }
  }

#pragma unroll
  for (int i = 0; i < 4; ++i) {
    float mx = -__builtin_inff(), mn = __builtin_inff(), s = 0.f, s2 = 0.f;
#pragma unroll
    for (int j = 0; j < 5; ++j) {
      float v = h[j][i];
      mx = fmaxf(mx, v); mn = fminf(mn, v); s += v; s2 += v * v;
    }
    int id = (p * 4 + kt) * O + ob + i;
    redm[id] = mx; redn[id] = mn; reds[id] = s; reds2[id] = s2;
  }
  __syncthreads();
  {
    int pp = t / O, o = t - (t / O) * O;
    float mx = -__builtin_inff(), mn = __builtin_inff(), s = 0.f, s2 = 0.f;
#pragma unroll
    for (int k4 = 0; k4 < 4; ++k4) {
      int id = (pp * 4 + k4) * O + o;
      mx = fmaxf(mx, redm[id]);
      mn = fminf(mn, redn[id]);
      s += reds[id];
      s2 += reds2[id];
    }
    size_t base = (size_t)(p0 + pp) * O + o;
    hmax[base] = mx; hmin[base] = mn; sarr[base] = s; s2arr[base] = s2;
  }
}

// ---------------- deterministic column reductions (fixed order, no atomics) -------
__global__ void colsum_partial_kernel(const float* __restrict__ A,
                                      const float* __restrict__ A2,
                                      float* __restrict__ ps, float* __restrict__ ps2,
                                      int O) {
  int o = blockIdx.x * 256 + threadIdx.x;
  if (o >= O) return;
  int p0 = blockIdx.y * 256;
  float s = 0.f, s2 = 0.f;
  for (int p = p0; p < p0 + 256; ++p) {
    s += A[(size_t)p * O + o];
    s2 += A2[(size_t)p * O + o];
  }
  ps[(size_t)blockIdx.y * O + o] = s;
  ps2[(size_t)blockIdx.y * O + o] = s2;
}

__global__ void colsumsq_partial_kernel(const float* __restrict__ A,
                                        float* __restrict__ ps, float* __restrict__ ps2,
                                        int O) {
  int o = blockIdx.x * 256 + threadIdx.x;
  if (o >= O) return;
  int p0 = blockIdx.y * 256;
  float s = 0.f, s2 = 0.f;
  for (int p = p0; p < p0 + 256; ++p) {
    float v = A[(size_t)p * O + o];
    s += v; s2 += v * v;
  }
  ps[(size_t)blockIdx.y * O + o] = s;
  ps2[(size_t)blockIdx.y * O + o] = s2;
}

__global__ void colsum_final_kernel(const float* __restrict__ ps,
                                    const float* __restrict__ ps2,
                                    float* __restrict__ ssum, float* __restrict__ ssq,
                                    int O) {
  int o = blockIdx.x * 256 + threadIdx.x;
  if (o >= O) return;
  float s = 0.f, s2 = 0.f;
  for (int c = 0; c < 32; ++c) {
    s += ps[(size_t)c * O + o];
    s2 += ps2[(size_t)c * O + o];
  }
  ssum[o] = s;
  ssq[o] = s2;
}

// ---------------- apply BN(+lrelu) to max (or min if gamma<0), write feats slice --
__global__ void bn_max_apply_kernel(
    const float* __restrict__ hmax, const float* __restrict__ hmin,
    const float* __restrict__ ssum, const float* __restrict__ ssq,
    const float* __restrict__ g, const float* __restrict__ bt,
    float* __restrict__ feats, int O, int off, float invcnt) {
  int i = blockIdx.x * 256 + threadIdx.x;
  if (i >= NB * NPTS * O) return;
  int r = i / O, o = i - r * O;
  float mean = ssum[o] * invcnt;
  float var = ssq[o] * invcnt - mean * mean;
  float a = g[o] * rsqrtf(var + BN_EPS);
  float h = (a >= 0.f) ? hmax[i] : hmin[i];
  float v = a * (h - mean) + bt[o];
  feats[(size_t)r * 512 + off + o] = lrelu_f(v);
}

// ---------------- global pool: BN+lrelu then max & mean over n (partials) ---------
__global__ void gpool_partial_kernel(
    const float* __restrict__ hglob, const float* __restrict__ ssum,
    const float* __restrict__ ssq, const float* __restrict__ gg,
    const float* __restrict__ bg, float* __restrict__ pmax, float* __restrict__ psum) {
  int b = blockIdx.y;
  int chunk = blockIdx.z;
  int o = blockIdx.x * 256 + threadIdx.x;
  float mean = ssum[o] * (1.f / 8192.f);
  float var = ssq[o] * (1.f / 8192.f) - mean * mean;
  float a = gg[o] * rsqrtf(var + BN_EPS);
  float c0 = bg[o] - a * mean;
  float mx = -__builtin_inff(), sm = 0.f;
  int n0 = chunk * 128;
  for (int n = n0; n < n0 + 128; ++n) {
    float h = hglob[((size_t)b * NPTS + n) * 1024 + o];
    float v = lrelu_f(a * h + c0);
    mx = fmaxf(mx, v);
    sm += v;
  }
  pmax[((size_t)b * 8 + chunk) * 1024 + o] = mx;
  psum[((size_t)b * 8 + chunk) * 1024 + o] = sm;
}

__global__ void gpool_merge_kernel(const float* __restrict__ pmax,
                                   const float* __restrict__ psum, float* __restrict__ z) {
  int i = blockIdx.x * 256 + threadIdx.x;  // 8*1024
  if (i >= NB * 1024) return;
  int b = i >> 10, o = i & 1023;
  float mx = -__builtin_inff(), sm = 0.f;
  for (int chunk = 0; chunk < 8; ++chunk) {
    mx = fmaxf(mx, pmax[((size_t)b * 8 + chunk) * 1024 + o]);
    sm += psum[((size_t)b * 8 + chunk) * 1024 + o];
  }
  z[b * 2048 + o] = mx;
  z[b * 2048 + 1024 + o] = sm * (1.f / 1024.f);
}

// ---------------- FC: out[s,o] = dot(in[s,:], W[o,:]) + bias (one wave per dot) ---
__global__ __launch_bounds__(64) void fc_wave_kernel(
    const float* __restrict__ in, const float* __restrict__ W,
    const float* __restrict__ bias, float* __restrict__ out, int IN, int OUT) {
  int o = blockIdx.x, s = blockIdx.y, t = threadIdx.x;
  const float* x = in + (size_t)s * IN;
  const float* w = W + (size_t)o * IN;
  float acc = 0.f;
  for (int c = t; c < IN; c += 64) acc += x[c] * w[c];
  for (int off = 32; off > 0; off >>= 1) acc += __shfl_down(acc, off);
  if (t == 0) out[(size_t)s * OUT + o] = acc + (bias ? bias[o] : 0.f);
}

// ---------------- BN over batch (8 rows) + lrelu, in place ----------------
__global__ void bn_rows_kernel(float* __restrict__ x, const float* __restrict__ g,
                               const float* __restrict__ bt, int O) {
  int o = blockIdx.x * blockDim.x + threadIdx.x;
  if (o >= O) return;
  float s = 0.f, s2 = 0.f;
#pragma unroll
  for (int r = 0; r < NB; ++r) { float v = x[r * O + o]; s += v; s2 += v * v; }
  float mean = s * 0.125f;
  float var = s2 * 0.125f - mean * mean;
  float a = g[o] * rsqrtf(var + BN_EPS);
  float c0 = bt[o] - a * mean;
#pragma unroll
  for (int r = 0; r < NB; ++r) x[r * O + o] = lrelu_f(a * x[r * O + o] + c0);
}

extern "C" void kernel_launch(void* const* d_in, const int* in_sizes, int n_in,
                              void* d_out, int out_size, void* d_ws, size_t ws_size,
                              hipStream_t stream) {
  const float* x   = (const float*)d_in[0];
  const float* W0  = (const float*)d_in[1];
  const float* g0  = (const float*)d_in[2];
  const float* b0  = (const float*)d_in[3];
  const float* W1  = (const float*)d_in[4];
  const float* g1  = (const float*)d_in[5];
  const float* b1  = (const float*)d_in[6];
  const float* W2  = (const float*)d_in[7];
  const float* g2  = (const float*)d_in[8];
  const float* b2  = (const float*)d_in[9];
  const float* W3  = (const float*)d_in[10];
  const float* g3  = (const float*)d_in[11];
  const float* b3  = (const float*)d_in[12];
  const float* Wg  = (const float*)d_in[13];
  const float* gg  = (const float*)d_in[14];
  const float* bg  = (const float*)d_in[15];
  const float* Wf1 = (const float*)d_in[16];
  const float* gf1 = (const float*)d_in[17];
  const float* bf1 = (const float*)d_in[18];
  const float* Wf2 = (const float*)d_in[19];
  const float* bf2w= (const float*)d_in[20];
  const float* gf2 = (const float*)d_in[21];
  const float* bf2 = (const float*)d_in[22];
  const float* Wf3 = (const float*)d_in[23];
  const float* bf3w= (const float*)d_in[24];
  // d_in[25] = k (==20, hardcoded)

  float* ws = (float*)d_ws;
  float* xt     = ws;                       // 24576
  float* xx     = xt + 24576;               // 8192
  int*   idxb   = (int*)(xx + 8192);        // 163840 ints
  float* feats  = (float*)(idxb + 163840);  // 4194304  [8192][512]
  float* scratch= feats + 4194304;          // 8388608 (dist | hmax+hmin+sarr+s2arr | hglob)
  float* dist   = scratch;
  float* hmax   = scratch;                  // [8192][O] <= 2M
  float* hmin   = scratch + 2097152;
  float* sarr   = scratch + 4194304;
  float* s2arr  = scratch + 6291456;
  float* hglob  = scratch;                  // [8192][1024] for gconv
  float* stats  = scratch + 8388608;        // 2048
  float* ssum   = stats;
  float* ssq    = stats + 1024;
  float* z      = stats + 2048;             // 16384
  float* pmax   = z + 16384;                // 65536
  float* psum   = pmax + 65536;             // 65536
  float* z2     = psum + 65536;             // 4096
  float* z3     = z2 + 4096;                // 2048
  float* wt0    = z3 + 2048;                // 384   (Wt: [2C][O])
  float* wt1    = wt0 + 384;                // 8192
  float* wt2    = wt1 + 8192;               // 16384
  float* wt3    = wt2 + 16384;              // 65536
  // Deterministic-reduction partials, aliased into serially-disjoint regions:
  float* part_s  = z;                       // 32*O <= 8192 (consumed before gpool_merge writes z)
  float* part_s2 = z + 8192;
  float* gpart_s  = pmax;                   // 32*1024 (consumed before gpool_partial writes pmax)
  float* gpart_s2 = psum;

  const float inv_cnt_edge = 1.f / (NB * NPTS * K_NBR);

  // ---- transpose x -> xt; transpose weights (pure data movement)
  transpose_kernel<<<dim3(96), dim3(256), 0, stream>>>(x, xt);
  wtrans_kernel<<<dim3(2),   dim3(256), 0, stream>>>(W0, wt0, 64, 6);
  wtrans_kernel<<<dim3(32),  dim3(256), 0, stream>>>(W1, wt1, 64, 128);
  wtrans_kernel<<<dim3(64),  dim3(256), 0, stream>>>(W2, wt2, 128, 128);
  wtrans_kernel<<<dim3(256), dim3(256), 0, stream>>>(W3, wt3, 256, 256);

  // ================= EdgeConv 1 (xt, C=3, O=64, off=0) =================
  rowsq_kernel<<<dim3(32), dim3(256), 0, stream>>>(xt, 3, 3, xx);
  gemm_nt_kernel<<<dim3(16, 16, 8), dim3(256), 0, stream>>>(
      xt, xt, dist, 1024, 1024, 3, 3, 3, 1024, 3072L, 3072L, 1048576L);
  topk_kernel<<<dim3(1024, 8), dim3(256), 0, stream>>>(dist, xx, idxb);
  edgeconv2_kernel<3, 64, 2><<<dim3(4096), dim3(64), 0, stream>>>(
      xt, 3, idxb, wt0, hmax, hmin, sarr, s2arr);
  colsum_partial_kernel<<<dim3(1, 32), dim3(256), 0, stream>>>(sarr, s2arr, part_s, part_s2, 64);
  colsum_final_kernel<<<dim3(1), dim3(256), 0, stream>>>(part_s, part_s2, ssum, ssq, 64);
  bn_max_apply_kernel<<<dim3((8192 * 64) / 256), dim3(256), 0, stream>>>(
      hmax, hmin, ssum, ssq, g0, b0, feats, 64, 0, inv_cnt_edge);

  // ================= EdgeConv 2 (f1, C=64, O=64, off=64) =================
  rowsq_kernel<<<dim3(32), dim3(256), 0, stream>>>(feats + 0, 512, 64, xx);
  gemm_nt_kernel<<<dim3(16, 16, 8), dim3(256), 0, stream>>>(
      feats + 0, feats + 0, dist, 1024, 1024, 64, 512, 512, 1024,
      524288L, 524288L, 1048576L);
  topk_kernel<<<dim3(1024, 8), dim3(256), 0, stream>>>(dist, xx, idxb);
  edgeconv3_kernel<64, 64><<<dim3(2048), dim3(256), 0, stream>>>(
      feats + 0, 512, idxb, wt1, hmax, hmin, sarr, s2arr);
  colsum_partial_kernel<<<dim3(1, 32), dim3(256), 0, stream>>>(sarr, s2arr, part_s, part_s2, 64);
  colsum_final_kernel<<<dim3(1), dim3(256), 0, stream>>>(part_s, part_s2, ssum, ssq, 64);
  bn_max_apply_kernel<<<dim3((8192 * 64) / 256), dim3(256), 0, stream>>>(
      hmax, hmin, ssum, ssq, g1, b1, feats, 64, 64, inv_cnt_edge);

  // ================= EdgeConv 3 (f2, C=64, O=128, off=128) =================
  rowsq_kernel<<<dim3(32), dim3(256), 0, stream>>>(feats + 64, 512, 64, xx);
  gemm_nt_kernel<<<dim3(16, 16, 8), dim3(256), 0, stream>>>(
      feats + 64, feats + 64, dist, 1024, 1024, 64, 512, 512, 1024,
      524288L, 524288L, 1048576L);
  topk_kernel<<<dim3(1024, 8), dim3(256), 0, stream>>>(dist, xx, idxb);
  edgeconv3_kernel<64, 128><<<dim3(4096), dim3(256), 0, stream>>>(
      feats + 64, 512, idxb, wt2, hmax, hmin, sarr, s2arr);
  colsum_partial_kernel<<<dim3(1, 32), dim3(256), 0, stream>>>(sarr, s2arr, part_s, part_s2, 128);
  colsum_final_kernel<<<dim3(1), dim3(256), 0, stream>>>(part_s, part_s2, ssum, ssq, 128);
  bn_max_apply_kernel<<<dim3((8192 * 128) / 256), dim3(256), 0, stream>>>(
      hmax, hmin, ssum, ssq, g2, b2, feats, 128, 128, inv_cnt_edge);

  // ================= EdgeConv 4 (f3, C=128, O=256, off=256) =================
  rowsq_kernel<<<dim3(32), dim3(256), 0, stream>>>(feats + 128, 512, 128, xx);
  gemm_nt_kernel<<<dim3(16, 16, 8), dim3(256), 0, stream>>>(
      feats + 128, feats + 128, dist, 1024, 1024, 128, 512, 512, 1024,
      524288L, 524288L, 1048576L);
  topk_kernel<<<dim3(1024, 8), dim3(256), 0, stream>>>(dist, xx, idxb);
  edgeconv3_kernel<128, 256><<<dim3(8192), dim3(256), 0, stream>>>(
      feats + 128, 512, idxb, wt3, hmax, hmin, sarr, s2arr);
  colsum_partial_kernel<<<dim3(1, 32), dim3(256), 0, stream>>>(sarr, s2arr, part_s, part_s2, 256);
  colsum_final_kernel<<<dim3(1), dim3(256), 0, stream>>>(part_s, part_s2, ssum, ssq, 256);
  bn_max_apply_kernel<<<dim3((8192 * 256) / 256), dim3(256), 0, stream>>>(
      hmax, hmin, ssum, ssq, g3, b3, feats, 256, 256, inv_cnt_edge);

  // ================= Global conv (feats @ Wg^T -> hglob) + BN + pool =========
  gemm_nt_kernel<<<dim3(16, 128, 1), dim3(256), 0, stream>>>(
      feats, Wg, hglob, 8192, 1024, 512, 512, 512, 1024, 0L, 0L, 0L);
  colsumsq_partial_kernel<<<dim3(4, 32), dim3(256), 0, stream>>>(hglob, gpart_s, gpart_s2, 1024);
  colsum_final_kernel<<<dim3(4), dim3(256), 0, stream>>>(gpart_s, gpart_s2, ssum, ssq, 1024);
  gpool_partial_kernel<<<dim3(4, 8, 8), dim3(256), 0, stream>>>(
      hglob, ssum, ssq, gg, bg, pmax, psum);
  gpool_merge_kernel<<<dim3(32), dim3(256), 0, stream>>>(pmax, psum, z);

  // ================= FC head =================
  fc_wave_kernel<<<dim3(512, 8), dim3(64), 0, stream>>>(z, Wf1, nullptr, z2, 2048, 512);
  bn_rows_kernel<<<dim3(2), dim3(256), 0, stream>>>(z2, gf1, bf1, 512);
  fc_wave_kernel<<<dim3(256, 8), dim3(64), 0, stream>>>(z2, Wf2, bf2w, z3, 512, 256);
  bn_rows_kernel<<<dim3(1), dim3(256), 0, stream>>>(z3, gf2, bf2, 256);
  fc_wave_kernel<<<dim3(67, 8), dim3(64), 0, stream>>>(z3, Wf3, bf3w, (float*)d_out, 256, 67);
}

// Round 14
// 1462.761 us; speedup vs baseline: 1.5613x; 1.0627x over previous
//
#include <hip/hip_runtime.h>
#include <math.h>

#define K_NBR 20
#define BN_EPS 1e-5f
#define NPTS 1024
#define NB 8

__device__ __forceinline__ float lrelu_f(float v) { return v >= 0.f ? v : 0.2f * v; }

// ---------------- transpose x [B,3,N] -> xt [B,N,3] ----------------
__global__ void transpose_kernel(const float* __restrict__ x, float* __restrict__ xt) {
  int i = blockIdx.x * 256 + threadIdx.x;
  if (i >= NB * 3 * NPTS) return;
  int b = i / (3 * NPTS);
  int rem = i - b * 3 * NPTS;
  int c = rem / NPTS;
  int n = rem - c * NPTS;
  xt[((size_t)b * NPTS + n) * 3 + c] = x[i];
}

// ---------------- W [O][C2] -> Wt [C2][O] (pure transpose, no value change) ------
__global__ void wtrans_kernel(const float* __restrict__ W, float* __restrict__ Wt,
                              int O, int C2) {
  int i = blockIdx.x * 256 + threadIdx.x;
  if (i >= O * C2) return;
  int o = i / C2, c = i - o * C2;
  Wt[(size_t)c * O + o] = W[i];
}

// ---------------- row squared norms ----------------
__global__ void rowsq_kernel(const float* __restrict__ X, int stride, int C,
                             float* __restrict__ xx) {
  int i = blockIdx.x * 256 + threadIdx.x;
  if (i >= NB * NPTS) return;
  const float* r = X + (size_t)i * stride;
  float s = 0.f;
  for (int c = 0; c < C; ++c) s += r[c] * r[c];
  xx[i] = s;
}

// ---------------- tiled f32 NT-GEMM (64x64 tile): C[r,o]=sum_k A[r,k]*B[o,k] -----
__device__ __forceinline__ float4 load_guard4(const float* __restrict__ rowp, int c, int K) {
  float4 v;
  if (c + 4 <= K) {
    v = *(const float4*)&rowp[c];
  } else {
    v.x = (c + 0 < K) ? rowp[c + 0] : 0.f;
    v.y = (c + 1 < K) ? rowp[c + 1] : 0.f;
    v.z = (c + 2 < K) ? rowp[c + 2] : 0.f;
    v.w = (c + 3 < K) ? rowp[c + 3] : 0.f;
  }
  return v;
}

__global__ __launch_bounds__(256) void gemm_nt_kernel(
    const float* __restrict__ A, const float* __restrict__ B, float* __restrict__ Cm,
    int M, int N, int K, int lda, int ldb, int ldc,
    long batchA, long batchB, long batchC) {
  const float* Ab = A + (size_t)blockIdx.z * batchA;
  const float* Bb = B + (size_t)blockIdx.z * batchB;
  float* Cb = Cm + (size_t)blockIdx.z * batchC;
  __shared__ float As[64][36];
  __shared__ float Bs[64][36];
  int t = threadIdx.x;
  int tx = t & 15, ty = t >> 4;
  int bm = blockIdx.y * 64, bn = blockIdx.x * 64;
  float acc[4][4] = {};
  for (int k0 = 0; k0 < K; k0 += 32) {
#pragma unroll
    for (int i = 0; i < 2; ++i) {
      int li = t * 2 + i;             // 0..511 float4 slots
      int r = li >> 3;
      int c = (li & 7) << 2;
      float4 va = load_guard4(Ab + (size_t)(bm + r) * lda, k0 + c, K);
      As[r][c] = va.x; As[r][c + 1] = va.y; As[r][c + 2] = va.z; As[r][c + 3] = va.w;
      float4 vb = load_guard4(Bb + (size_t)(bn + r) * ldb, k0 + c, K);
      Bs[r][c] = vb.x; Bs[r][c + 1] = vb.y; Bs[r][c + 2] = vb.z; Bs[r][c + 3] = vb.w;
    }
    __syncthreads();
#pragma unroll
    for (int kc = 0; kc < 32; kc += 4) {
      float4 a4[4], b4[4];
#pragma unroll
      for (int i = 0; i < 4; ++i) a4[i] = *(const float4*)&As[ty + 16 * i][kc];
#pragma unroll
      for (int j = 0; j < 4; ++j) b4[j] = *(const float4*)&Bs[tx + 16 * j][kc];
#pragma unroll
      for (int i = 0; i < 4; ++i)
#pragma unroll
        for (int j = 0; j < 4; ++j)
          acc[i][j] += a4[i].x * b4[j].x + a4[i].y * b4[j].y +
                       a4[i].z * b4[j].z + a4[i].w * b4[j].w;
    }
    __syncthreads();
  }
#pragma unroll
  for (int i = 0; i < 4; ++i) {
    int r = bm + ty + 16 * i;
#pragma unroll
    for (int j = 0; j < 4; ++j) {
      int o = bn + tx + 16 * j;
      Cb[(size_t)r * ldc + o] = acc[i][j];
    }
  }
}

// ---------------- top-k (k=20), validated 256-thread LDS version ------------------
__global__ __launch_bounds__(256) void topk_kernel(
    const float* __restrict__ inner, const float* __restrict__ xx, int* __restrict__ idxb) {
  int b = blockIdx.y, n = blockIdx.x, t = threadIdx.x;
  __shared__ float nd[NPTS];
  __shared__ float rv[256];
  __shared__ int ri[256];
  float xxn = xx[b * NPTS + n];
  const float* row = inner + ((size_t)b * NPTS + n) * NPTS;
  for (int m = t; m < NPTS; m += 256)
    nd[m] = 2.f * row[m] - xxn - xx[b * NPTS + m];
  __syncthreads();
  for (int kk = 0; kk < K_NBR; ++kk) {
    float bv = -__builtin_inff(); int bi = NPTS;
    for (int m = t; m < NPTS; m += 256) {
      float v = nd[m];
      if (v > bv || (v == bv && m < bi)) { bv = v; bi = m; }
    }
    rv[t] = bv; ri[t] = bi;
    __syncthreads();
    for (int s = 128; s > 0; s >>= 1) {
      if (t < s) {
        float ov = rv[t + s]; int oi = ri[t + s];
        if (ov > rv[t] || (ov == rv[t] && oi < ri[t])) { rv[t] = ov; ri[t] = oi; }
      }
      __syncthreads();
    }
    if (t == 0) {
      idxb[((size_t)b * NPTS + n) * K_NBR + kk] = ri[0];
      nd[ri[0]] = -__builtin_inff();
    }
    __syncthreads();
  }
}

// ---------------- edge conv (round-2 arithmetic), small-P version for C=3 ---------
template <int C, int O, int P>
__global__ __launch_bounds__(O) void edgeconv2_kernel(
    const float* __restrict__ X, int stride, const int* __restrict__ idxb,
    const float* __restrict__ Wt, float* __restrict__ hmax, float* __restrict__ hmin,
    float* __restrict__ sarr, float* __restrict__ s2arr) {
  constexpr int TPB = O;
  int t = threadIdx.x;
  int p0 = blockIdx.x * P;
  __shared__ float center[P][C];
  __shared__ float diff[P][K_NBR][C];
  __shared__ int sidx[P][K_NBR];
  for (int i = t; i < P * C; i += TPB) {
    int p = i / C, c = i - p * C;
    center[p][c] = X[(size_t)(p0 + p) * stride + c];
  }
  if (t < P * K_NBR) {
    int p = t / K_NBR, k = t - p * K_NBR;
    sidx[p][k] = idxb[(size_t)(p0 + p) * K_NBR + k];
  }
  __syncthreads();
  for (int i = t; i < P * K_NBR * C; i += TPB) {
    int p = i / (K_NBR * C);
    int rem = i - p * (K_NBR * C);
    int kk = rem / C, c = rem - kk * C;
    int bbase = ((p0 + p) >> 10) << 10;
    diff[p][kk][c] = X[(size_t)(bbase + sidx[p][kk]) * stride + c] - center[p][c];
  }
  __syncthreads();

  int o = t;
  float h[P][K_NBR];
  {
    float wc[P];
#pragma unroll
    for (int p = 0; p < P; ++p) wc[p] = 0.f;
    for (int c = 0; c < C; ++c) {
      float wv = Wt[(size_t)(C + c) * O + o];
#pragma unroll
      for (int p = 0; p < P; ++p) wc[p] += wv * center[p][c];
    }
#pragma unroll
    for (int p = 0; p < P; ++p)
#pragma unroll
      for (int kk = 0; kk < K_NBR; ++kk) h[p][kk] = wc[p];
  }

  if constexpr (C % 4 == 0) {
    for (int c = 0; c < C; c += 4) {
      float w0 = Wt[(size_t)(c + 0) * O + o];
      float w1 = Wt[(size_t)(c + 1) * O + o];
      float w2 = Wt[(size_t)(c + 2) * O + o];
      float w3 = Wt[(size_t)(c + 3) * O + o];
#pragma unroll
      for (int p = 0; p < P; ++p)
#pragma unroll
        for (int kk = 0; kk < K_NBR; ++kk) {
          float4 d = *(const float4*)&diff[p][kk][c];
          h[p][kk] += w0 * d.x + w1 * d.y + w2 * d.z + w3 * d.w;
        }
    }
  } else {
    for (int c = 0; c < C; ++c) {
      float wv = Wt[(size_t)c * O + o];
#pragma unroll
      for (int p = 0; p < P; ++p)
#pragma unroll
        for (int kk = 0; kk < K_NBR; ++kk) h[p][kk] += wv * diff[p][kk][c];
    }
  }

#pragma unroll
  for (int p = 0; p < P; ++p) {
    float s = 0.f, s2 = 0.f, mx = -__builtin_inff(), mn = __builtin_inff();
#pragma unroll
    for (int kk = 0; kk < K_NBR; ++kk) {
      float v = h[p][kk];
      s += v; s2 += v * v; mx = fmaxf(mx, v); mn = fminf(mn, v);
    }
    size_t base = (size_t)(p0 + p) * O + o;
    hmax[base] = mx;
    hmin[base] = mn;
    sarr[base] = s;
    s2arr[base] = s2;
  }
}

// ---------------- register-tiled edge conv v2: kt in low lane bits ----------------
// thread = (p, ot, kt): kt = r&3 (lane bits 0..1), ot = r>>2, 5 kk x 4 o per thread.
// Per-chunk FMA expression BIT-IDENTICAL to edgeconv3/edgeconv2 C%4==0 path.
// Cross-kt combine via __shfl_xor butterfly (deterministic); s/s2 reassociate only.
// LDS: padded diff rows (C+4 floats = 16B-aligned stride, distinct banks per kt).
template <int C, int O>
__global__ __launch_bounds__(256) void edgeconv4_kernel(
    const float* __restrict__ X, int stride, const int* __restrict__ idxb,
    const float* __restrict__ Wt, float* __restrict__ hmax, float* __restrict__ hmin,
    float* __restrict__ sarr, float* __restrict__ s2arr) {
  constexpr int PPB = 256 / O;          // points per block (1,2,4)
  constexpr int C4 = C / 4;
  constexpr int LDC = C + 4;            // padded row stride in floats (16B-aligned)
  int t = threadIdx.x;
  int p0 = blockIdx.x * PPB;
  __shared__ float center[PPB][C];
  __shared__ float diff[PPB][K_NBR][LDC];
  __shared__ int sidx[PPB][K_NBR];
  __shared__ float wcs[256];

  for (int i = t; i < PPB * C4; i += 256) {
    int p = i / C4, c4 = i - p * C4;
    *(float4*)&center[p][c4 * 4] =
        *(const float4*)&X[(size_t)(p0 + p) * stride + c4 * 4];
  }
  if (t < PPB * K_NBR) {
    int p = t / K_NBR, k = t - p * K_NBR;
    sidx[p][k] = idxb[(size_t)(p0 + p) * K_NBR + k];
  }
  __syncthreads();
  for (int i = t; i < PPB * K_NBR * C4; i += 256) {
    int p = i / (K_NBR * C4);
    int rem = i - p * (K_NBR * C4);
    int kk = rem / C4, c4 = rem - kk * C4;
    int bbase = ((p0 + p) >> 10) << 10;
    float4 xv = *(const float4*)&X[(size_t)(bbase + sidx[p][kk]) * stride + c4 * 4];
    float4 cv = *(const float4*)&center[p][c4 * 4];
    float4 dv;
    dv.x = xv.x - cv.x; dv.y = xv.y - cv.y; dv.z = xv.z - cv.z; dv.w = xv.w - cv.w;
    *(float4*)&diff[p][kk][c4 * 4] = dv;
  }
  {
    // wc for (p = t/O, o = t%O): ascending-c scalar association (same as before)
    int p = t / O, o = t - (t / O) * O;
    float acc = 0.f;
    for (int c = 0; c < C; ++c) acc += Wt[(size_t)(C + c) * O + o] * center[p][c];
    wcs[t] = acc;
  }
  __syncthreads();

  int p = t / O;
  int r = t - p * O;
  int kt = r & 3;       // lane bits 0..1 -> shfl_xor(1/2) stays in-group
  int ot = r >> 2;
  int ob = ot * 4;

  float h[5][4];
#pragma unroll
  for (int j = 0; j < 5; ++j)
#pragma unroll
    for (int i = 0; i < 4; ++i) h[j][i] = wcs[p * O + ob + i];

  for (int c = 0; c < C; c += 4) {
    float4 w0 = *(const float4*)&Wt[(size_t)(c + 0) * O + ob];
    float4 w1 = *(const float4*)&Wt[(size_t)(c + 1) * O + ob];
    float4 w2 = *(const float4*)&Wt[(size_t)(c + 2) * O + ob];
    float4 w3 = *(const float4*)&Wt[(size_t)(c + 3) * O + ob];
#pragma unroll
    for (int j = 0; j < 5; ++j) {
      float4 d = *(const float4*)&diff[p][kt * 5 + j][c];
      h[j][0] += w0.x * d.x + w1.x * d.y + w2.x * d.z + w3.x * d.w;
      h[j][1] += w0.y * d.x + w1.y * d.y + w2.y * d.z + w3.y * d.w;
      h[j][2] += w0.z * d.x + w1.z * d.y + w2.z * d.z + w3.z * d.w;
      h[j][3] += w0.w * d.x + w1.w * d.y + w2.w * d.z + w3.w * d.w;
    }
  }

  float4 mx4, mn4, s4, s24;
  float* mx4a = &mx4.x; float* mn4a = &mn4.x; float* s4a = &s4.x; float* s24a = &s24.x;
#pragma unroll
  for (int i = 0; i < 4; ++i) {
    float mx = -__builtin_inff(), mn = __builtin_inff(), s = 0.f, s2 = 0.f;
#pragma unroll
    for (int j = 0; j < 5; ++j) {
      float v = h[j][i];
      mx = fmaxf(mx, v); mn = fminf(mn, v); s += v; s2 += v * v;
    }
    mx = fmaxf(mx, __shfl_xor(mx, 1)); mx = fmaxf(mx, __shfl_xor(mx, 2));
    mn = fminf(mn, __shfl_xor(mn, 1)); mn = fminf(mn, __shfl_xor(mn, 2));
    s += __shfl_xor(s, 1);  s += __shfl_xor(s, 2);
    s2 += __shfl_xor(s2, 1); s2 += __shfl_xor(s2, 2);
    mx4a[i] = mx; mn4a[i] = mn; s4a[i] = s; s24a[i] = s2;
  }
  if (kt == 0) {
    size_t base = (size_t)(p0 + p) * O + ob;
    *(float4*)&hmax[base] = mx4;
    *(float4*)&hmin[base] = mn4;
    *(float4*)&sarr[base] = s4;
    *(float4*)&s2arr[base] = s24;
  }
}

// ---------------- deterministic column reductions (fixed order, no atomics) -------
__global__ void colsum_partial_kernel(const float* __restrict__ A,
                                      const float* __restrict__ A2,
                                      float* __restrict__ ps, float* __restrict__ ps2,
                                      int O) {
  int o = blockIdx.x * 256 + threadIdx.x;
  if (o >= O) return;
  int p0 = blockIdx.y * 256;
  float s = 0.f, s2 = 0.f;
  for (int p = p0; p < p0 + 256; ++p) {
    s += A[(size_t)p * O + o];
    s2 += A2[(size_t)p * O + o];
  }
  ps[(size_t)blockIdx.y * O + o] = s;
  ps2[(size_t)blockIdx.y * O + o] = s2;
}

__global__ void colsumsq_partial_kernel(const float* __restrict__ A,
                                        float* __restrict__ ps, float* __restrict__ ps2,
                                        int O) {
  int o = blockIdx.x * 256 + threadIdx.x;
  if (o >= O) return;
  int p0 = blockIdx.y * 256;
  float s = 0.f, s2 = 0.f;
  for (int p = p0; p < p0 + 256; ++p) {
    float v = A[(size_t)p * O + o];
    s += v; s2 += v * v;
  }
  ps[(size_t)blockIdx.y * O + o] = s;
  ps2[(size_t)blockIdx.y * O + o] = s2;
}

__global__ void colsum_final_kernel(const float* __restrict__ ps,
                                    const float* __restrict__ ps2,
                                    float* __restrict__ ssum, float* __restrict__ ssq,
                                    int O) {
  int o = blockIdx.x * 256 + threadIdx.x;
  if (o >= O) return;
  float s = 0.f, s2 = 0.f;
  for (int c = 0; c < 32; ++c) {
    s += ps[(size_t)c * O + o];
    s2 += ps2[(size_t)c * O + o];
  }
  ssum[o] = s;
  ssq[o] = s2;
}

// ---------------- apply BN(+lrelu) to max (or min if gamma<0), write feats slice --
__global__ void bn_max_apply_kernel(
    const float* __restrict__ hmax, const float* __restrict__ hmin,
    const float* __restrict__ ssum, const float* __restrict__ ssq,
    const float* __restrict__ g, const float* __restrict__ bt,
    float* __restrict__ feats, int O, int off, float invcnt) {
  int i = blockIdx.x * 256 + threadIdx.x;
  if (i >= NB * NPTS * O) return;
  int r = i / O, o = i - r * O;
  float mean = ssum[o] * invcnt;
  float var = ssq[o] * invcnt - mean * mean;
  float a = g[o] * rsqrtf(var + BN_EPS);
  float h = (a >= 0.f) ? hmax[i] : hmin[i];
  float v = a * (h - mean) + bt[o];
  feats[(size_t)r * 512 + off + o] = lrelu_f(v);
}

// ---------------- global pool: BN+lrelu then max & mean over n (partials) ---------
__global__ void gpool_partial_kernel(
    const float* __restrict__ hglob, const float* __restrict__ ssum,
    const float* __restrict__ ssq, const float* __restrict__ gg,
    const float* __restrict__ bg, float* __restrict__ pmax, float* __restrict__ psum) {
  int b = blockIdx.y;
  int chunk = blockIdx.z;
  int o = blockIdx.x * 256 + threadIdx.x;
  float mean = ssum[o] * (1.f / 8192.f);
  float var = ssq[o] * (1.f / 8192.f) - mean * mean;
  float a = gg[o] * rsqrtf(var + BN_EPS);
  float c0 = bg[o] - a * mean;
  float mx = -__builtin_inff(), sm = 0.f;
  int n0 = chunk * 128;
  for (int n = n0; n < n0 + 128; ++n) {
    float h = hglob[((size_t)b * NPTS + n) * 1024 + o];
    float v = lrelu_f(a * h + c0);
    mx = fmaxf(mx, v);
    sm += v;
  }
  pmax[((size_t)b * 8 + chunk) * 1024 + o] = mx;
  psum[((size_t)b * 8 + chunk) * 1024 + o] = sm;
}

__global__ void gpool_merge_kernel(const float* __restrict__ pmax,
                                   const float* __restrict__ psum, float* __restrict__ z) {
  int i = blockIdx.x * 256 + threadIdx.x;  // 8*1024
  if (i >= NB * 1024) return;
  int b = i >> 10, o = i & 1023;
  float mx = -__builtin_inff(), sm = 0.f;
  for (int chunk = 0; chunk < 8; ++chunk) {
    mx = fmaxf(mx, pmax[((size_t)b * 8 + chunk) * 1024 + o]);
    sm += psum[((size_t)b * 8 + chunk) * 1024 + o];
  }
  z[b * 2048 + o] = mx;
  z[b * 2048 + 1024 + o] = sm * (1.f / 1024.f);
}

// ---------------- FC: out[s,o] = dot(in[s,:], W[o,:]) + bias (one wave per dot) ---
__global__ __launch_bounds__(64) void fc_wave_kernel(
    const float* __restrict__ in, const float* __restrict__ W,
    const float* __restrict__ bias, float* __restrict__ out, int IN, int OUT) {
  int o = blockIdx.x, s = blockIdx.y, t = threadIdx.x;
  const float* x = in + (size_t)s * IN;
  const float* w = W + (size_t)o * IN;
  float acc = 0.f;
  for (int c = t; c < IN; c += 64) acc += x[c] * w[c];
  for (int off = 32; off > 0; off >>= 1) acc += __shfl_down(acc, off);
  if (t == 0) out[(size_t)s * OUT + o] = acc + (bias ? bias[o] : 0.f);
}

// ---------------- BN over batch (8 rows) + lrelu, in place ----------------
__global__ void bn_rows_kernel(float* __restrict__ x, const float* __restrict__ g,
                               const float* __restrict__ bt, int O) {
  int o = blockIdx.x * blockDim.x + threadIdx.x;
  if (o >= O) return;
  float s = 0.f, s2 = 0.f;
#pragma unroll
  for (int r = 0; r < NB; ++r) { float v = x[r * O + o]; s += v; s2 += v * v; }
  float mean = s * 0.125f;
  float var = s2 * 0.125f - mean * mean;
  float a = g[o] * rsqrtf(var + BN_EPS);
  float c0 = bt[o] - a * mean;
#pragma unroll
  for (int r = 0; r < NB; ++r) x[r * O + o] = lrelu_f(a * x[r * O + o] + c0);
}

extern "C" void kernel_launch(void* const* d_in, const int* in_sizes, int n_in,
                              void* d_out, int out_size, void* d_ws, size_t ws_size,
                              hipStream_t stream) {
  const float* x   = (const float*)d_in[0];
  const float* W0  = (const float*)d_in[1];
  const float* g0  = (const float*)d_in[2];
  const float* b0  = (const float*)d_in[3];
  const float* W1  = (const float*)d_in[4];
  const float* g1  = (const float*)d_in[5];
  const float* b1  = (const float*)d_in[6];
  const float* W2  = (const float*)d_in[7];
  const float* g2  = (const float*)d_in[8];
  const float* b2  = (const float*)d_in[9];
  const float* W3  = (const float*)d_in[10];
  const float* g3  = (const float*)d_in[11];
  const float* b3  = (const float*)d_in[12];
  const float* Wg  = (const float*)d_in[13];
  const float* gg  = (const float*)d_in[14];
  const float* bg  = (const float*)d_in[15];
  const float* Wf1 = (const float*)d_in[16];
  const float* gf1 = (const float*)d_in[17];
  const float* bf1 = (const float*)d_in[18];
  const float* Wf2 = (const float*)d_in[19];
  const float* bf2w= (const float*)d_in[20];
  const float* gf2 = (const float*)d_in[21];
  const float* bf2 = (const float*)d_in[22];
  const float* Wf3 = (const float*)d_in[23];
  const float* bf3w= (const float*)d_in[24];
  // d_in[25] = k (==20, hardcoded)

  float* ws = (float*)d_ws;
  float* xt     = ws;                       // 24576
  float* xx     = xt + 24576;               // 8192
  int*   idxb   = (int*)(xx + 8192);        // 163840 ints
  float* feats  = (float*)(idxb + 163840);  // 4194304  [8192][512]
  float* scratch= feats + 4194304;          // 8388608 (dist | hmax+hmin+sarr+s2arr | hglob)
  float* dist   = scratch;
  float* hmax   = scratch;                  // [8192][O] <= 2M
  float* hmin   = scratch + 2097152;
  float* sarr   = scratch + 4194304;
  float* s2arr  = scratch + 6291456;
  float* hglob  = scratch;                  // [8192][1024] for gconv
  float* stats  = scratch + 8388608;        // 2048
  float* ssum   = stats;
  float* ssq    = stats + 1024;
  float* z      = stats + 2048;             // 16384
  float* pmax   = z + 16384;                // 65536
  float* psum   = pmax + 65536;             // 65536
  float* z2     = psum + 65536;             // 4096
  float* z3     = z2 + 4096;                // 2048
  float* wt0    = z3 + 2048;                // 384   (Wt: [2C][O])
  float* wt1    = wt0 + 384;                // 8192
  float* wt2    = wt1 + 8192;               // 16384
  float* wt3    = wt2 + 16384;              // 65536
  // Deterministic-reduction partials, aliased into serially-disjoint regions:
  float* part_s  = z;                       // 32*O <= 8192 (consumed before gpool_merge writes z)
  float* part_s2 = z + 8192;
  float* gpart_s  = pmax;                   // 32*1024 (consumed before gpool_partial writes pmax)
  float* gpart_s2 = psum;

  const float inv_cnt_edge = 1.f / (NB * NPTS * K_NBR);

  // ---- transpose x -> xt; transpose weights (pure data movement)
  transpose_kernel<<<dim3(96), dim3(256), 0, stream>>>(x, xt);
  wtrans_kernel<<<dim3(2),   dim3(256), 0, stream>>>(W0, wt0, 64, 6);
  wtrans_kernel<<<dim3(32),  dim3(256), 0, stream>>>(W1, wt1, 64, 128);
  wtrans_kernel<<<dim3(64),  dim3(256), 0, stream>>>(W2, wt2, 128, 128);
  wtrans_kernel<<<dim3(256), dim3(256), 0, stream>>>(W3, wt3, 256, 256);

  // ================= EdgeConv 1 (xt, C=3, O=64, off=0) =================
  rowsq_kernel<<<dim3(32), dim3(256), 0, stream>>>(xt, 3, 3, xx);
  gemm_nt_kernel<<<dim3(16, 16, 8), dim3(256), 0, stream>>>(
      xt, xt, dist, 1024, 1024, 3, 3, 3, 1024, 3072L, 3072L, 1048576L);
  topk_kernel<<<dim3(1024, 8), dim3(256), 0, stream>>>(dist, xx, idxb);
  edgeconv2_kernel<3, 64, 2><<<dim3(4096), dim3(64), 0, stream>>>(
      xt, 3, idxb, wt0, hmax, hmin, sarr, s2arr);
  colsum_partial_kernel<<<dim3(1, 32), dim3(256), 0, stream>>>(sarr, s2arr, part_s, part_s2, 64);
  colsum_final_kernel<<<dim3(1), dim3(256), 0, stream>>>(part_s, part_s2, ssum, ssq, 64);
  bn_max_apply_kernel<<<dim3((8192 * 64) / 256), dim3(256), 0, stream>>>(
      hmax, hmin, ssum, ssq, g0, b0, feats, 64, 0, inv_cnt_edge);

  // ================= EdgeConv 2 (f1, C=64, O=64, off=64) =================
  rowsq_kernel<<<dim3(32), dim3(256), 0, stream>>>(feats + 0, 512, 64, xx);
  gemm_nt_kernel<<<dim3(16, 16, 8), dim3(256), 0, stream>>>(
      feats + 0, feats + 0, dist, 1024, 1024, 64, 512, 512, 1024,
      524288L, 524288L, 1048576L);
  topk_kernel<<<dim3(1024, 8), dim3(256), 0, stream>>>(dist, xx, idxb);
  edgeconv4_kernel<64, 64><<<dim3(2048), dim3(256), 0, stream>>>(
      feats + 0, 512, idxb, wt1, hmax, hmin, sarr, s2arr);
  colsum_partial_kernel<<<dim3(1, 32), dim3(256), 0, stream>>>(sarr, s2arr, part_s, part_s2, 64);
  colsum_final_kernel<<<dim3(1), dim3(256), 0, stream>>>(part_s, part_s2, ssum, ssq, 64);
  bn_max_apply_kernel<<<dim3((8192 * 64) / 256), dim3(256), 0, stream>>>(
      hmax, hmin, ssum, ssq, g1, b1, feats, 64, 64, inv_cnt_edge);

  // ================= EdgeConv 3 (f2, C=64, O=128, off=128) =================
  rowsq_kernel<<<dim3(32), dim3(256), 0, stream>>>(feats + 64, 512, 64, xx);
  gemm_nt_kernel<<<dim3(16, 16, 8), dim3(256), 0, stream>>>(
      feats + 64, feats + 64, dist, 1024, 1024, 64, 512, 512, 1024,
      524288L, 524288L, 1048576L);
  topk_kernel<<<dim3(1024, 8), dim3(256), 0, stream>>>(dist, xx, idxb);
  edgeconv4_kernel<64, 128><<<dim3(4096), dim3(256), 0, stream>>>(
      feats + 64, 512, idxb, wt2, hmax, hmin, sarr, s2arr);
  colsum_partial_kernel<<<dim3(1, 32), dim3(256), 0, stream>>>(sarr, s2arr, part_s, part_s2, 128);
  colsum_final_kernel<<<dim3(1), dim3(256), 0, stream>>>(part_s, part_s2, ssum, ssq, 128);
  bn_max_apply_kernel<<<dim3((8192 * 128) / 256), dim3(256), 0, stream>>>(
      hmax, hmin, ssum, ssq, g2, b2, feats, 128, 128, inv_cnt_edge);

  // ================= EdgeConv 4 (f3, C=128, O=256, off=256) =================
  rowsq_kernel<<<dim3(32), dim3(256), 0, stream>>>(feats + 128, 512, 128, xx);
  gemm_nt_kernel<<<dim3(16, 16, 8), dim3(256), 0, stream>>>(
      feats + 128, feats + 128, dist, 1024, 1024, 128, 512, 512, 1024,
      524288L, 524288L, 1048576L);
  topk_kernel<<<dim3(1024, 8), dim3(256), 0, stream>>>(dist, xx, idxb);
  edgeconv4_kernel<128, 256><<<dim3(8192), dim3(256), 0, stream>>>(
      feats + 128, 512, idxb, wt3, hmax, hmin, sarr, s2arr);
  colsum_partial_kernel<<<dim3(1, 32), dim3(256), 0, stream>>>(sarr, s2arr, part_s, part_s2, 256);
  colsum_final_kernel<<<dim3(1), dim3(256), 0, stream>>>(part_s, part_s2, ssum, ssq, 256);
  bn_max_apply_kernel<<<dim3((8192 * 256) / 256), dim3(256), 0, stream>>>(
      hmax, hmin, ssum, ssq, g3, b3, feats, 256, 256, inv_cnt_edge);

  // ================= Global conv (feats @ Wg^T -> hglob) + BN + pool =========
  gemm_nt_kernel<<<dim3(16, 128, 1), dim3(256), 0, stream>>>(
      feats, Wg, hglob, 8192, 1024, 512, 512, 512, 1024, 0L, 0L, 0L);
  colsumsq_partial_kernel<<<dim3(4, 32), dim3(256), 0, stream>>>(hglob, gpart_s, gpart_s2, 1024);
  colsum_final_kernel<<<dim3(4), dim3(256), 0, stream>>>(gpart_s, gpart_s2, ssum, ssq, 1024);
  gpool_partial_kernel<<<dim3(4, 8, 8), dim3(256), 0, stream>>>(
      hglob, ssum, ssq, gg, bg, pmax, psum);
  gpool_merge_kernel<<<dim3(32), dim3(256), 0, stream>>>(pmax, psum, z);

  // ================= FC head =================
  fc_wave_kernel<<<dim3(512, 8), dim3(64), 0, stream>>>(z, Wf1, nullptr, z2, 2048, 512);
  bn_rows_kernel<<<dim3(2), dim3(256), 0, stream>>>(z2, gf1, bf1, 512);
  fc_wave_kernel<<<dim3(256, 8), dim3(64), 0, stream>>>(z2, Wf2, bf2w, z3, 512, 256);
  bn_rows_kernel<<<dim3(1), dim3(256), 0, stream>>>(z3, gf2, bf2, 256);
  fc_wave_kernel<<<dim3(67, 8), dim3(64), 0, stream>>>(z3, Wf3, bf3w, (float*)d_out, 256, 67);
}

// Round 15
// 1029.963 us; speedup vs baseline: 2.2174x; 1.4202x over previous
//
#include <hip/hip_runtime.h>
#include <math.h>

#define K_NBR 20
#define BN_EPS 1e-5f
#define NPTS 1024
#define NB 8

__device__ __forceinline__ float lrelu_f(float v) { return v >= 0.f ? v : 0.2f * v; }

// ---------------- transpose x [B,3,N] -> xt [B,N,3] ----------------
__global__ void transpose_kernel(const float* __restrict__ x, float* __restrict__ xt) {
  int i = blockIdx.x * 256 + threadIdx.x;
  if (i >= NB * 3 * NPTS) return;
  int b = i / (3 * NPTS);
  int rem = i - b * 3 * NPTS;
  int c = rem / NPTS;
  int n = rem - c * NPTS;
  xt[((size_t)b * NPTS + n) * 3 + c] = x[i];
}

// ---------------- W [O][C2] -> Wt [C2][O] (pure transpose, no value change) ------
__global__ void wtrans_kernel(const float* __restrict__ W, float* __restrict__ Wt,
                              int O, int C2) {
  int i = blockIdx.x * 256 + threadIdx.x;
  if (i >= O * C2) return;
  int o = i / C2, c = i - o * C2;
  Wt[(size_t)c * O + o] = W[i];
}

// ---------------- row squared norms ----------------
__global__ void rowsq_kernel(const float* __restrict__ X, int stride, int C,
                             float* __restrict__ xx) {
  int i = blockIdx.x * 256 + threadIdx.x;
  if (i >= NB * NPTS) return;
  const float* r = X + (size_t)i * stride;
  float s = 0.f;
  for (int c = 0; c < C; ++c) s += r[c] * r[c];
  xx[i] = s;
}

// ---------------- tiled f32 NT-GEMM (64x64 tile): C[r,o]=sum_k A[r,k]*B[o,k] -----
__device__ __forceinline__ float4 load_guard4(const float* __restrict__ rowp, int c, int K) {
  float4 v;
  if (c + 4 <= K) {
    v = *(const float4*)&rowp[c];
  } else {
    v.x = (c + 0 < K) ? rowp[c + 0] : 0.f;
    v.y = (c + 1 < K) ? rowp[c + 1] : 0.f;
    v.z = (c + 2 < K) ? rowp[c + 2] : 0.f;
    v.w = (c + 3 < K) ? rowp[c + 3] : 0.f;
  }
  return v;
}

__global__ __launch_bounds__(256) void gemm_nt_kernel(
    const float* __restrict__ A, const float* __restrict__ B, float* __restrict__ Cm,
    int M, int N, int K, int lda, int ldb, int ldc,
    long batchA, long batchB, long batchC) {
  const float* Ab = A + (size_t)blockIdx.z * batchA;
  const float* Bb = B + (size_t)blockIdx.z * batchB;
  float* Cb = Cm + (size_t)blockIdx.z * batchC;
  __shared__ float As[64][36];
  __shared__ float Bs[64][36];
  int t = threadIdx.x;
  int tx = t & 15, ty = t >> 4;
  int bm = blockIdx.y * 64, bn = blockIdx.x * 64;
  float acc[4][4] = {};
  for (int k0 = 0; k0 < K; k0 += 32) {
#pragma unroll
    for (int i = 0; i < 2; ++i) {
      int li = t * 2 + i;             // 0..511 float4 slots
      int r = li >> 3;
      int c = (li & 7) << 2;
      float4 va = load_guard4(Ab + (size_t)(bm + r) * lda, k0 + c, K);
      As[r][c] = va.x; As[r][c + 1] = va.y; As[r][c + 2] = va.z; As[r][c + 3] = va.w;
      float4 vb = load_guard4(Bb + (size_t)(bn + r) * ldb, k0 + c, K);
      Bs[r][c] = vb.x; Bs[r][c + 1] = vb.y; Bs[r][c + 2] = vb.z; Bs[r][c + 3] = vb.w;
    }
    __syncthreads();
#pragma unroll
    for (int kc = 0; kc < 32; kc += 4) {
      float4 a4[4], b4[4];
#pragma unroll
      for (int i = 0; i < 4; ++i) a4[i] = *(const float4*)&As[ty + 16 * i][kc];
#pragma unroll
      for (int j = 0; j < 4; ++j) b4[j] = *(const float4*)&Bs[tx + 16 * j][kc];
#pragma unroll
      for (int i = 0; i < 4; ++i)
#pragma unroll
        for (int j = 0; j < 4; ++j)
          acc[i][j] += a4[i].x * b4[j].x + a4[i].y * b4[j].y +
                       a4[i].z * b4[j].z + a4[i].w * b4[j].w;
    }
    __syncthreads();
  }
#pragma unroll
  for (int i = 0; i < 4; ++i) {
    int r = bm + ty + 16 * i;
#pragma unroll
    for (int j = 0; j < 4; ++j) {
      int o = bn + tx + 16 * j;
      Cb[(size_t)r * ldc + o] = acc[i][j];
    }
  }
}

// ---------------- top-k (k=20), 1 wave per point, register-resident ---------------
// Bit-identical indices to the LDS topk: same nd expression, exact comparisons,
// same lower-index-wins tie rule (in-lane ascending scan + (val,idx) butterfly).
__global__ __launch_bounds__(64) void topk_wave_kernel(
    const float* __restrict__ inner, const float* __restrict__ xx, int* __restrict__ idxb) {
  int b = blockIdx.y, n = blockIdx.x, t = threadIdx.x;
  const float* row = inner + ((size_t)b * NPTS + n) * NPTS;
  float xxn = xx[b * NPTS + n];
  float v[16];
#pragma unroll
  for (int j = 0; j < 16; ++j) {
    int m = j * 64 + t;
    v[j] = 2.f * row[m] - xxn - xx[b * NPTS + m];
  }
  for (int kk = 0; kk < K_NBR; ++kk) {
    float bv = v[0];
    int bi = t;
#pragma unroll
    for (int j = 1; j < 16; ++j) {
      int m = j * 64 + t;                 // strictly increasing -> ties keep earlier
      if (v[j] > bv) { bv = v[j]; bi = m; }
    }
#pragma unroll
    for (int off = 32; off > 0; off >>= 1) {
      float ov = __shfl_xor(bv, off);
      int oi = __shfl_xor(bi, off);
      if (ov > bv || (ov == bv && oi < bi)) { bv = ov; bi = oi; }
    }
    if (t == 0) idxb[((size_t)b * NPTS + n) * K_NBR + kk] = bi;
#pragma unroll
    for (int j = 0; j < 16; ++j)
      if (bi == j * 64 + t) v[j] = -__builtin_inff();
  }
}

// ---------------- edge conv (round-2 arithmetic), small-P version for C=3 ---------
template <int C, int O, int P>
__global__ __launch_bounds__(O) void edgeconv2_kernel(
    const float* __restrict__ X, int stride, const int* __restrict__ idxb,
    const float* __restrict__ Wt, float* __restrict__ hmax, float* __restrict__ hmin,
    float* __restrict__ sarr, float* __restrict__ s2arr) {
  constexpr int TPB = O;
  int t = threadIdx.x;
  int p0 = blockIdx.x * P;
  __shared__ float center[P][C];
  __shared__ float diff[P][K_NBR][C];
  __shared__ int sidx[P][K_NBR];
  for (int i = t; i < P * C; i += TPB) {
    int p = i / C, c = i - p * C;
    center[p][c] = X[(size_t)(p0 + p) * stride + c];
  }
  if (t < P * K_NBR) {
    int p = t / K_NBR, k = t - p * K_NBR;
    sidx[p][k] = idxb[(size_t)(p0 + p) * K_NBR + k];
  }
  __syncthreads();
  for (int i = t; i < P * K_NBR * C; i += TPB) {
    int p = i / (K_NBR * C);
    int rem = i - p * (K_NBR * C);
    int kk = rem / C, c = rem - kk * C;
    int bbase = ((p0 + p) >> 10) << 10;
    diff[p][kk][c] = X[(size_t)(bbase + sidx[p][kk]) * stride + c] - center[p][c];
  }
  __syncthreads();

  int o = t;
  float h[P][K_NBR];
  {
    float wc[P];
#pragma unroll
    for (int p = 0; p < P; ++p) wc[p] = 0.f;
    for (int c = 0; c < C; ++c) {
      float wv = Wt[(size_t)(C + c) * O + o];
#pragma unroll
      for (int p = 0; p < P; ++p) wc[p] += wv * center[p][c];
    }
#pragma unroll
    for (int p = 0; p < P; ++p)
#pragma unroll
      for (int kk = 0; kk < K_NBR; ++kk) h[p][kk] = wc[p];
  }

  if constexpr (C % 4 == 0) {
    for (int c = 0; c < C; c += 4) {
      float w0 = Wt[(size_t)(c + 0) * O + o];
      float w1 = Wt[(size_t)(c + 1) * O + o];
      float w2 = Wt[(size_t)(c + 2) * O + o];
      float w3 = Wt[(size_t)(c + 3) * O + o];
#pragma unroll
      for (int p = 0; p < P; ++p)
#pragma unroll
        for (int kk = 0; kk < K_NBR; ++kk) {
          float4 d = *(const float4*)&diff[p][kk][c];
          h[p][kk] += w0 * d.x + w1 * d.y + w2 * d.z + w3 * d.w;
        }
    }
  } else {
    for (int c = 0; c < C; ++c) {
      float wv = Wt[(size_t)c * O + o];
#pragma unroll
      for (int p = 0; p < P; ++p)
#pragma unroll
        for (int kk = 0; kk < K_NBR; ++kk) h[p][kk] += wv * diff[p][kk][c];
    }
  }

#pragma unroll
  for (int p = 0; p < P; ++p) {
    float s = 0.f, s2 = 0.f, mx = -__builtin_inff(), mn = __builtin_inff();
#pragma unroll
    for (int kk = 0; kk < K_NBR; ++kk) {
      float v = h[p][kk];
      s += v; s2 += v * v; mx = fmaxf(mx, v); mn = fminf(mn, v);
    }
    size_t base = (size_t)(p0 + p) * O + o;
    hmax[base] = mx;
    hmin[base] = mn;
    sarr[base] = s;
    s2arr[base] = s2;
  }
}

// ---------------- register-tiled edge conv v2: kt in low lane bits ----------------
template <int C, int O>
__global__ __launch_bounds__(256) void edgeconv4_kernel(
    const float* __restrict__ X, int stride, const int* __restrict__ idxb,
    const float* __restrict__ Wt, float* __restrict__ hmax, float* __restrict__ hmin,
    float* __restrict__ sarr, float* __restrict__ s2arr) {
  constexpr int PPB = 256 / O;          // points per block (1,2,4)
  constexpr int C4 = C / 4;
  constexpr int LDC = C + 4;            // padded row stride in floats (16B-aligned)
  int t = threadIdx.x;
  int p0 = blockIdx.x * PPB;
  __shared__ float center[PPB][C];
  __shared__ float diff[PPB][K_NBR][LDC];
  __shared__ int sidx[PPB][K_NBR];
  __shared__ float wcs[256];

  for (int i = t; i < PPB * C4; i += 256) {
    int p = i / C4, c4 = i - p * C4;
    *(float4*)&center[p][c4 * 4] =
        *(const float4*)&X[(size_t)(p0 + p) * stride + c4 * 4];
  }
  if (t < PPB * K_NBR) {
    int p = t / K_NBR, k = t - p * K_NBR;
    sidx[p][k] = idxb[(size_t)(p0 + p) * K_NBR + k];
  }
  __syncthreads();
  for (int i = t; i < PPB * K_NBR * C4; i += 256) {
    int p = i / (K_NBR * C4);
    int rem = i - p * (K_NBR * C4);
    int kk = rem / C4, c4 = rem - kk * C4;
    int bbase = ((p0 + p) >> 10) << 10;
    float4 xv = *(const float4*)&X[(size_t)(bbase + sidx[p][kk]) * stride + c4 * 4];
    float4 cv = *(const float4*)&center[p][c4 * 4];
    float4 dv;
    dv.x = xv.x - cv.x; dv.y = xv.y - cv.y; dv.z = xv.z - cv.z; dv.w = xv.w - cv.w;
    *(float4*)&diff[p][kk][c4 * 4] = dv;
  }
  {
    int p = t / O, o = t - (t / O) * O;
    float acc = 0.f;
    for (int c = 0; c < C; ++c) acc += Wt[(size_t)(C + c) * O + o] * center[p][c];
    wcs[t] = acc;
  }
  __syncthreads();

  int p = t / O;
  int r = t - p * O;
  int kt = r & 3;       // lane bits 0..1 -> shfl_xor(1/2) stays in-group
  int ot = r >> 2;
  int ob = ot * 4;

  float h[5][4];
#pragma unroll
  for (int j = 0; j < 5; ++j)
#pragma unroll
    for (int i = 0; i < 4; ++i) h[j][i] = wcs[p * O + ob + i];

  for (int c = 0; c < C; c += 4) {
    float4 w0 = *(const float4*)&Wt[(size_t)(c + 0) * O + ob];
    float4 w1 = *(const float4*)&Wt[(size_t)(c + 1) * O + ob];
    float4 w2 = *(const float4*)&Wt[(size_t)(c + 2) * O + ob];
    float4 w3 = *(const float4*)&Wt[(size_t)(c + 3) * O + ob];
#pragma unroll
    for (int j = 0; j < 5; ++j) {
      float4 d = *(const float4*)&diff[p][kt * 5 + j][c];
      h[j][0] += w0.x * d.x + w1.x * d.y + w2.x * d.z + w3.x * d.w;
      h[j][1] += w0.y * d.x + w1.y * d.y + w2.y * d.z + w3.y * d.w;
      h[j][2] += w0.z * d.x + w1.z * d.y + w2.z * d.z + w3.z * d.w;
      h[j][3] += w0.w * d.x + w1.w * d.y + w2.w * d.z + w3.w * d.w;
    }
  }

  float4 mx4, mn4, s4, s24;
  float* mx4a = &mx4.x; float* mn4a = &mn4.x; float* s4a = &s4.x; float* s24a = &s24.x;
#pragma unroll
  for (int i = 0; i < 4; ++i) {
    float mx = -__builtin_inff(), mn = __builtin_inff(), s = 0.f, s2 = 0.f;
#pragma unroll
    for (int j = 0; j < 5; ++j) {
      float v = h[j][i];
      mx = fmaxf(mx, v); mn = fminf(mn, v); s += v; s2 += v * v;
    }
    mx = fmaxf(mx, __shfl_xor(mx, 1)); mx = fmaxf(mx, __shfl_xor(mx, 2));
    mn = fminf(mn, __shfl_xor(mn, 1)); mn = fminf(mn, __shfl_xor(mn, 2));
    s += __shfl_xor(s, 1);  s += __shfl_xor(s, 2);
    s2 += __shfl_xor(s2, 1); s2 += __shfl_xor(s2, 2);
    mx4a[i] = mx; mn4a[i] = mn; s4a[i] = s; s24a[i] = s2;
  }
  if (kt == 0) {
    size_t base = (size_t)(p0 + p) * O + ob;
    *(float4*)&hmax[base] = mx4;
    *(float4*)&hmin[base] = mn4;
    *(float4*)&sarr[base] = s4;
    *(float4*)&s2arr[base] = s24;
  }
}

// ---------------- deterministic column reductions (fixed order, no atomics) -------
__global__ void colsum_partial_kernel(const float* __restrict__ A,
                                      const float* __restrict__ A2,
                                      float* __restrict__ ps, float* __restrict__ ps2,
                                      int O) {
  int o = blockIdx.x * 256 + threadIdx.x;
  if (o >= O) return;
  int p0 = blockIdx.y * 256;
  float s = 0.f, s2 = 0.f;
  for (int p = p0; p < p0 + 256; ++p) {
    s += A[(size_t)p * O + o];
    s2 += A2[(size_t)p * O + o];
  }
  ps[(size_t)blockIdx.y * O + o] = s;
  ps2[(size_t)blockIdx.y * O + o] = s2;
}

__global__ void colsumsq_partial_kernel(const float* __restrict__ A,
                                        float* __restrict__ ps, float* __restrict__ ps2,
                                        int O) {
  int o = blockIdx.x * 256 + threadIdx.x;
  if (o >= O) return;
  int p0 = blockIdx.y * 256;
  float s = 0.f, s2 = 0.f;
  for (int p = p0; p < p0 + 256; ++p) {
    float v = A[(size_t)p * O + o];
    s += v; s2 += v * v;
  }
  ps[(size_t)blockIdx.y * O + o] = s;
  ps2[(size_t)blockIdx.y * O + o] = s2;
}

__global__ void colsum_final_kernel(const float* __restrict__ ps,
                                    const float* __restrict__ ps2,
                                    float* __restrict__ ssum, float* __restrict__ ssq,
                                    int O) {
  int o = blockIdx.x * 256 + threadIdx.x;
  if (o >= O) return;
  float s = 0.f, s2 = 0.f;
  for (int c = 0; c < 32; ++c) {
    s += ps[(size_t)c * O + o];
    s2 += ps2[(size_t)c * O + o];
  }
  ssum[o] = s;
  ssq[o] = s2;
}

// ---------------- apply BN(+lrelu) to max (or min if gamma<0), write feats slice --
__global__ void bn_max_apply_kernel(
    const float* __restrict__ hmax, const float* __restrict__ hmin,
    const float* __restrict__ ssum, const float* __restrict__ ssq,
    const float* __restrict__ g, const float* __restrict__ bt,
    float* __restrict__ feats, int O, int off, float invcnt) {
  int i = blockIdx.x * 256 + threadIdx.x;
  if (i >= NB * NPTS * O) return;
  int r = i / O, o = i - r * O;
  float mean = ssum[o] * invcnt;
  float var = ssq[o] * invcnt - mean * mean;
  float a = g[o] * rsqrtf(var + BN_EPS);
  float h = (a >= 0.f) ? hmax[i] : hmin[i];
  float v = a * (h - mean) + bt[o];
  feats[(size_t)r * 512 + off + o] = lrelu_f(v);
}

// ---------------- global pool: BN+lrelu then max & mean over n (partials) ---------
__global__ void gpool_partial_kernel(
    const float* __restrict__ hglob, const float* __restrict__ ssum,
    const float* __restrict__ ssq, const float* __restrict__ gg,
    const float* __restrict__ bg, float* __restrict__ pmax, float* __restrict__ psum) {
  int b = blockIdx.y;
  int chunk = blockIdx.z;
  int o = blockIdx.x * 256 + threadIdx.x;
  float mean = ssum[o] * (1.f / 8192.f);
  float var = ssq[o] * (1.f / 8192.f) - mean * mean;
  float a = gg[o] * rsqrtf(var + BN_EPS);
  float c0 = bg[o] - a * mean;
  float mx = -__builtin_inff(), sm = 0.f;
  int n0 = chunk * 128;
  for (int n = n0; n < n0 + 128; ++n) {
    float h = hglob[((size_t)b * NPTS + n) * 1024 + o];
    float v = lrelu_f(a * h + c0);
    mx = fmaxf(mx, v);
    sm += v;
  }
  pmax[((size_t)b * 8 + chunk) * 1024 + o] = mx;
  psum[((size_t)b * 8 + chunk) * 1024 + o] = sm;
}

__global__ void gpool_merge_kernel(const float* __restrict__ pmax,
                                   const float* __restrict__ psum, float* __restrict__ z) {
  int i = blockIdx.x * 256 + threadIdx.x;  // 8*1024
  if (i >= NB * 1024) return;
  int b = i >> 10, o = i & 1023;
  float mx = -__builtin_inff(), sm = 0.f;
  for (int chunk = 0; chunk < 8; ++chunk) {
    mx = fmaxf(mx, pmax[((size_t)b * 8 + chunk) * 1024 + o]);
    sm += psum[((size_t)b * 8 + chunk) * 1024 + o];
  }
  z[b * 2048 + o] = mx;
  z[b * 2048 + 1024 + o] = sm * (1.f / 1024.f);
}

// ---------------- FC: out[s,o] = dot(in[s,:], W[o,:]) + bias (one wave per dot) ---
__global__ __launch_bounds__(64) void fc_wave_kernel(
    const float* __restrict__ in, const float* __restrict__ W,
    const float* __restrict__ bias, float* __restrict__ out, int IN, int OUT) {
  int o = blockIdx.x, s = blockIdx.y, t = threadIdx.x;
  const float* x = in + (size_t)s * IN;
  const float* w = W + (size_t)o * IN;
  float acc = 0.f;
  for (int c = t; c < IN; c += 64) acc += x[c] * w[c];
  for (int off = 32; off > 0; off >>= 1) acc += __shfl_down(acc, off);
  if (t == 0) out[(size_t)s * OUT + o] = acc + (bias ? bias[o] : 0.f);
}

// ---------------- BN over batch (8 rows) + lrelu, in place ----------------
__global__ void bn_rows_kernel(float* __restrict__ x, const float* __restrict__ g,
                               const float* __restrict__ bt, int O) {
  int o = blockIdx.x * blockDim.x + threadIdx.x;
  if (o >= O) return;
  float s = 0.f, s2 = 0.f;
#pragma unroll
  for (int r = 0; r < NB; ++r) { float v = x[r * O + o]; s += v; s2 += v * v; }
  float mean = s * 0.125f;
  float var = s2 * 0.125f - mean * mean;
  float a = g[o] * rsqrtf(var + BN_EPS);
  float c0 = bt[o] - a * mean;
#pragma unroll
  for (int r = 0; r < NB; ++r) x[r * O + o] = lrelu_f(a * x[r * O + o] + c0);
}

extern "C" void kernel_launch(void* const* d_in, const int* in_sizes, int n_in,
                              void* d_out, int out_size, void* d_ws, size_t ws_size,
                              hipStream_t stream) {
  const float* x   = (const float*)d_in[0];
  const float* W0  = (const float*)d_in[1];
  const float* g0  = (const float*)d_in[2];
  const float* b0  = (const float*)d_in[3];
  const float* W1  = (const float*)d_in[4];
  const float* g1  = (const float*)d_in[5];
  const float* b1  = (const float*)d_in[6];
  const float* W2  = (const float*)d_in[7];
  const float* g2  = (const float*)d_in[8];
  const float* b2  = (const float*)d_in[9];
  const float* W3  = (const float*)d_in[10];
  const float* g3  = (const float*)d_in[11];
  const float* b3  = (const float*)d_in[12];
  const float* Wg  = (const float*)d_in[13];
  const float* gg  = (const float*)d_in[14];
  const float* bg  = (const float*)d_in[15];
  const float* Wf1 = (const float*)d_in[16];
  const float* gf1 = (const float*)d_in[17];
  const float* bf1 = (const float*)d_in[18];
  const float* Wf2 = (const float*)d_in[19];
  const float* bf2w= (const float*)d_in[20];
  const float* gf2 = (const float*)d_in[21];
  const float* bf2 = (const float*)d_in[22];
  const float* Wf3 = (const float*)d_in[23];
  const float* bf3w= (const float*)d_in[24];
  // d_in[25] = k (==20, hardcoded)

  float* ws = (float*)d_ws;
  float* xt     = ws;                       // 24576
  float* xx     = xt + 24576;               // 8192
  int*   idxb   = (int*)(xx + 8192);        // 163840 ints
  float* feats  = (float*)(idxb + 163840);  // 4194304  [8192][512]
  float* scratch= feats + 4194304;          // 8388608 (dist | hmax+hmin+sarr+s2arr | hglob)
  float* dist   = scratch;
  float* hmax   = scratch;                  // [8192][O] <= 2M
  float* hmin   = scratch + 2097152;
  float* sarr   = scratch + 4194304;
  float* s2arr  = scratch + 6291456;
  float* hglob  = scratch;                  // [8192][1024] for gconv
  float* stats  = scratch + 8388608;        // 2048
  float* ssum   = stats;
  float* ssq    = stats + 1024;
  float* z      = stats + 2048;             // 16384
  float* pmax   = z + 16384;                // 65536
  float* psum   = pmax + 65536;             // 65536
  float* z2     = psum + 65536;             // 4096
  float* z3     = z2 + 4096;                // 2048
  float* wt0    = z3 + 2048;                // 384   (Wt: [2C][O])
  float* wt1    = wt0 + 384;                // 8192
  float* wt2    = wt1 + 8192;               // 16384
  float* wt3    = wt2 + 16384;              // 65536
  // Deterministic-reduction partials, aliased into serially-disjoint regions:
  float* part_s  = z;                       // 32*O <= 8192 (consumed before gpool_merge writes z)
  float* part_s2 = z + 8192;
  float* gpart_s  = pmax;                   // 32*1024 (consumed before gpool_partial writes pmax)
  float* gpart_s2 = psum;

  const float inv_cnt_edge = 1.f / (NB * NPTS * K_NBR);

  // ---- transpose x -> xt; transpose weights (pure data movement)
  transpose_kernel<<<dim3(96), dim3(256), 0, stream>>>(x, xt);
  wtrans_kernel<<<dim3(2),   dim3(256), 0, stream>>>(W0, wt0, 64, 6);
  wtrans_kernel<<<dim3(32),  dim3(256), 0, stream>>>(W1, wt1, 64, 128);
  wtrans_kernel<<<dim3(64),  dim3(256), 0, stream>>>(W2, wt2, 128, 128);
  wtrans_kernel<<<dim3(256), dim3(256), 0, stream>>>(W3, wt3, 256, 256);

  // ================= EdgeConv 1 (xt, C=3, O=64, off=0) =================
  rowsq_kernel<<<dim3(32), dim3(256), 0, stream>>>(xt, 3, 3, xx);
  gemm_nt_kernel<<<dim3(16, 16, 8), dim3(256), 0, stream>>>(
      xt, xt, dist, 1024, 1024, 3, 3, 3, 1024, 3072L, 3072L, 1048576L);
  topk_wave_kernel<<<dim3(1024, 8), dim3(64), 0, stream>>>(dist, xx, idxb);
  edgeconv2_kernel<3, 64, 2><<<dim3(4096), dim3(64), 0, stream>>>(
      xt, 3, idxb, wt0, hmax, hmin, sarr, s2arr);
  colsum_partial_kernel<<<dim3(1, 32), dim3(256), 0, stream>>>(sarr, s2arr, part_s, part_s2, 64);
  colsum_final_kernel<<<dim3(1), dim3(256), 0, stream>>>(part_s, part_s2, ssum, ssq, 64);
  bn_max_apply_kernel<<<dim3((8192 * 64) / 256), dim3(256), 0, stream>>>(
      hmax, hmin, ssum, ssq, g0, b0, feats, 64, 0, inv_cnt_edge);

  // ================= EdgeConv 2 (f1, C=64, O=64, off=64) =================
  rowsq_kernel<<<dim3(32), dim3(256), 0, stream>>>(feats + 0, 512, 64, xx);
  gemm_nt_kernel<<<dim3(16, 16, 8), dim3(256), 0, stream>>>(
      feats + 0, feats + 0, dist, 1024, 1024, 64, 512, 512, 1024,
      524288L, 524288L, 1048576L);
  topk_wave_kernel<<<dim3(1024, 8), dim3(64), 0, stream>>>(dist, xx, idxb);
  edgeconv4_kernel<64, 64><<<dim3(2048), dim3(256), 0, stream>>>(
      feats + 0, 512, idxb, wt1, hmax, hmin, sarr, s2arr);
  colsum_partial_kernel<<<dim3(1, 32), dim3(256), 0, stream>>>(sarr, s2arr, part_s, part_s2, 64);
  colsum_final_kernel<<<dim3(1), dim3(256), 0, stream>>>(part_s, part_s2, ssum, ssq, 64);
  bn_max_apply_kernel<<<dim3((8192 * 64) / 256), dim3(256), 0, stream>>>(
      hmax, hmin, ssum, ssq, g1, b1, feats, 64, 64, inv_cnt_edge);

  // ================= EdgeConv 3 (f2, C=64, O=128, off=128) =================
  rowsq_kernel<<<dim3(32), dim3(256), 0, stream>>>(feats + 64, 512, 64, xx);
  gemm_nt_kernel<<<dim3(16, 16, 8), dim3(256), 0, stream>>>(
      feats + 64, feats + 64, dist, 1024, 1024, 64, 512, 512, 1024,
      524288L, 524288L, 1048576L);
  topk_wave_kernel<<<dim3(1024, 8), dim3(64), 0, stream>>>(dist, xx, idxb);
  edgeconv4_kernel<64, 128><<<dim3(4096), dim3(256), 0, stream>>>(
      feats + 64, 512, idxb, wt2, hmax, hmin, sarr, s2arr);
  colsum_partial_kernel<<<dim3(1, 32), dim3(256), 0, stream>>>(sarr, s2arr, part_s, part_s2, 128);
  colsum_final_kernel<<<dim3(1), dim3(256), 0, stream>>>(part_s, part_s2, ssum, ssq, 128);
  bn_max_apply_kernel<<<dim3((8192 * 128) / 256), dim3(256), 0, stream>>>(
      hmax, hmin, ssum, ssq, g2, b2, feats, 128, 128, inv_cnt_edge);

  // ================= EdgeConv 4 (f3, C=128, O=256, off=256) =================
  rowsq_kernel<<<dim3(32), dim3(256), 0, stream>>>(feats + 128, 512, 128, xx);
  gemm_nt_kernel<<<dim3(16, 16, 8), dim3(256), 0, stream>>>(
      feats + 128, feats + 128, dist, 1024, 1024, 128, 512, 512, 1024,
      524288L, 524288L, 1048576L);
  topk_wave_kernel<<<dim3(1024, 8), dim3(64), 0, stream>>>(dist, xx, idxb);
  edgeconv4_kernel<128, 256><<<dim3(8192), dim3(256), 0, stream>>>(
      feats + 128, 512, idxb, wt3, hmax, hmin, sarr, s2arr);
  colsum_partial_kernel<<<dim3(1, 32), dim3(256), 0, stream>>>(sarr, s2arr, part_s, part_s2, 256);
  colsum_final_kernel<<<dim3(1), dim3(256), 0, stream>>>(part_s, part_s2, ssum, ssq, 256);
  bn_max_apply_kernel<<<dim3((8192 * 256) / 256), dim3(256), 0, stream>>>(
      hmax, hmin, ssum, ssq, g3, b3, feats, 256, 256, inv_cnt_edge);

  // ================= Global conv (feats @ Wg^T -> hglob) + BN + pool =========
  gemm_nt_kernel<<<dim3(16, 128, 1), dim3(256), 0, stream>>>(
      feats, Wg, hglob, 8192, 1024, 512, 512, 512, 1024, 0L, 0L, 0L);
  colsumsq_partial_kernel<<<dim3(4, 32), dim3(256), 0, stream>>>(hglob, gpart_s, gpart_s2, 1024);
  colsum_final_kernel<<<dim3(4), dim3(256), 0, stream>>>(gpart_s, gpart_s2, ssum, ssq, 1024);
  gpool_partial_kernel<<<dim3(4, 8, 8), dim3(256), 0, stream>>>(
      hglob, ssum, ssq, gg, bg, pmax, psum);
  gpool_merge_kernel<<<dim3(32), dim3(256), 0, stream>>>(pmax, psum, z);

  // ================= FC head =================
  fc_wave_kernel<<<dim3(512, 8), dim3(64), 0, stream>>>(z, Wf1, nullptr, z2, 2048, 512);
  bn_rows_kernel<<<dim3(2), dim3(256), 0, stream>>>(z2, gf1, bf1, 512);
  fc_wave_kernel<<<dim3(256, 8), dim3(64), 0, stream>>>(z2, Wf2, bf2w, z3, 512, 256);
  bn_rows_kernel<<<dim3(1), dim3(256), 0, stream>>>(z3, gf2, bf2, 256);
  fc_wave_kernel<<<dim3(67, 8), dim3(64), 0, stream>>>(z3, Wf3, bf3w, (float*)d_out, 256, 67);
}